// Round 12
// baseline (225.171 us; speedup 1.0000x reference)
//
#include <hip/hip_runtime.h>
#include <hip/hip_fp16.h>
#include <math.h>

#define NN 50000
#define NE 800000
#define NG 256
#define NEG_SLOPE 0.2f
#define GEPS 1e-5f
#define CHUNK 64
#define NB 196          // coarse buckets of 256 node-ids (dst >> 8)
#define CAP 6144        // per-bucket segment capacity (mean 4081)
#define NAB 261         // binA blocks = ceil(NE/EPB)
#define EPB 3072        // edges per binA block (12/thread, int4-aligned)
#define NLINB 782       // (NN+63)/64 lin blocks
#define EPT 3321        // alpha edges per tail block = ceil((NE+NN)/NG)
#define GMAX 512        // fallback gate capacity
#define GLDS 280        // staged rows per graph (actual max ~240)
#define SXP 264         // padded s_x row stride in halves (528 B -> bank-safe)

typedef _Float16 f16x8 __attribute__((ext_vector_type(8)));
typedef _Float16 f16x4 __attribute__((ext_vector_type(4)));
typedef float f32x4 __attribute__((ext_vector_type(4)));
typedef float f32x2 __attribute__((ext_vector_type(2)));

__device__ __forceinline__ float lrelu(float v){ return v > 0.f ? v : NEG_SLOPE * v; }

// ---------------- K0: weight converts + goff + bucket zero + w_att build -----
__global__ __launch_bounds__(256) void k_misc(const float* __restrict__ lin_w,
                                              _Float16* __restrict__ wh,
                                              const float* __restrict__ att1_w,
                                              _Float16* __restrict__ a1w,
                                              const float* __restrict__ att_src,
                                              const float* __restrict__ att_dst,
                                              _Float16* __restrict__ watt,
                                              const int* __restrict__ batch,
                                              int* __restrict__ goff,
                                              int* __restrict__ gcnt,
                                              int* __restrict__ bucket_cnt) {
  int b = blockIdx.x, tid = threadIdx.x;
  if (b == 0) {
    if (tid < NB) bucket_cnt[tid] = 0;
    int g = tid;
    int lo = 0, hi = NN;
    while (lo < hi) { int mid = (lo + hi) >> 1; if (batch[mid] < g) lo = mid + 1; else hi = mid; }
    int start = lo;
    lo = 0; hi = NN;
    while (lo < hi) { int mid = (lo + hi) >> 1; if (batch[mid] < g + 1) lo = mid + 1; else hi = mid; }
    goff[g] = start;
    gcnt[g] = lo - start;
  } else if (b <= 16) {
    int i0 = (b - 1) * 1024 + tid * 4;
    float4 f = *(const float4*)&lin_w[i0];
    f16x4 h4;
    h4[0] = (_Float16)f.x; h4[1] = (_Float16)f.y; h4[2] = (_Float16)f.z; h4[3] = (_Float16)f.w;
    *(f16x4*)&wh[i0] = h4;
  } else if (b <= 20) {
    int i0 = (b - 17) * 1024 + tid * 4;
    float4 f = *(const float4*)&att1_w[i0];
    f16x4 h4;
    h4[0] = (_Float16)f.x; h4[1] = (_Float16)f.y; h4[2] = (_Float16)f.z; h4[3] = (_Float16)f.w;
    *(f16x4*)&a1w[i0] = h4;
  } else {
    for (int e = tid; e < 16 * 64; e += 256) {
      int row = e >> 6, k = e & 63;
      float s = 0.f;
      if (row < 8) {
        int h = row & 3;
        const float* av = (row < 4) ? att_src : att_dst;
        for (int c = 0; c < 64; c++)
          s += av[h * 64 + c] * lin_w[(h * 64 + c) * 64 + k];
      }
      watt[e] = (_Float16)s;
    }
  }
}

// ---------------- K1 fused: MFMA lin (blocks < NLINB) | binA sort (rest) ------
__device__ __forceinline__ void lin_body(char* smem,
                                         const float* __restrict__ x,
                                         const _Float16* __restrict__ wh,
                                         const _Float16* __restrict__ watt,
                                         unsigned char* __restrict__ xh8,
                                         float* __restrict__ a_src_n,
                                         float* __restrict__ a_dst_n) {
  unsigned char* s_f8 = (unsigned char*)smem;     // 16 KB (4 waves x 4 KB)
  int w = threadIdx.x >> 6, lane = threadIdx.x & 63;
  int nb = blockIdx.x * 64 + w * 16;
  if (nb >= NN) return;                 // per-wave LDS region; no barriers used
  int am = lane & 15, quad = lane >> 4;
  int wb = w * 4096;

  const float* xr = x + (size_t)(nb + am) * 64 + quad * 8;
  float4 f0 = *(const float4*)(xr);
  float4 f1 = *(const float4*)(xr + 4);
  float4 f2 = *(const float4*)(xr + 32);
  float4 f3 = *(const float4*)(xr + 36);
  f16x8 a0, a1;
  a0[0] = (_Float16)f0.x; a0[1] = (_Float16)f0.y; a0[2] = (_Float16)f0.z; a0[3] = (_Float16)f0.w;
  a0[4] = (_Float16)f1.x; a0[5] = (_Float16)f1.y; a0[6] = (_Float16)f1.z; a0[7] = (_Float16)f1.w;
  a1[0] = (_Float16)f2.x; a1[1] = (_Float16)f2.y; a1[2] = (_Float16)f2.z; a1[3] = (_Float16)f2.w;
  a1[4] = (_Float16)f3.x; a1[5] = (_Float16)f3.y; a1[6] = (_Float16)f3.z; a1[7] = (_Float16)f3.w;

  f32x4 acc[16];
#pragma unroll
  for (int ct = 0; ct < 16; ct++) acc[ct] = (f32x4){0.f, 0.f, 0.f, 0.f};

#pragma unroll
  for (int ct = 0; ct < 16; ct++) {
    const _Float16* wbp = wh + (size_t)(ct * 16 + am) * 64 + quad * 8;
    f16x8 b0 = *(const f16x8*)(wbp);
    f16x8 b1 = *(const f16x8*)(wbp + 32);
    acc[ct] = __builtin_amdgcn_mfma_f32_16x16x32_f16(a0, b0, acc[ct], 0, 0, 0);
    acc[ct] = __builtin_amdgcn_mfma_f32_16x16x32_f16(a1, b1, acc[ct], 0, 0, 0);
  }

  // attention projections via one extra MFMA pair (replaces 128-shfl reduce)
  {
    const _Float16* wap = watt + am * 64 + quad * 8;
    f16x8 t0 = *(const f16x8*)(wap);
    f16x8 t1 = *(const f16x8*)(wap + 32);
    f32x4 acca = (f32x4){0.f, 0.f, 0.f, 0.f};
    acca = __builtin_amdgcn_mfma_f32_16x16x32_f16(a0, t0, acca, 0, 0, 0);
    acca = __builtin_amdgcn_mfma_f32_16x16x32_f16(a1, t1, acca, 0, 0, 0);
    if (am < 8) {
#pragma unroll
      for (int r = 0; r < 4; r++) {
        int node = nb + quad * 4 + r;
        if (am < 4) a_src_n[node * 4 + am] = acca[r];
        else        a_dst_n[node * 4 + (am - 4)] = acca[r];
      }
    }
  }

#pragma unroll
  for (int r = 0; r < 4; r++) {
    uint4 u;
    int t;
    t = __builtin_amdgcn_cvt_pk_fp8_f32(acc[0][r],  acc[1][r],  0, 0);
    t = __builtin_amdgcn_cvt_pk_fp8_f32(acc[2][r],  acc[3][r],  t, 1);
    u.x = (unsigned)t;
    t = __builtin_amdgcn_cvt_pk_fp8_f32(acc[4][r],  acc[5][r],  0, 0);
    t = __builtin_amdgcn_cvt_pk_fp8_f32(acc[6][r],  acc[7][r],  t, 1);
    u.y = (unsigned)t;
    t = __builtin_amdgcn_cvt_pk_fp8_f32(acc[8][r],  acc[9][r],  0, 0);
    t = __builtin_amdgcn_cvt_pk_fp8_f32(acc[10][r], acc[11][r], t, 1);
    u.z = (unsigned)t;
    t = __builtin_amdgcn_cvt_pk_fp8_f32(acc[12][r], acc[13][r], 0, 0);
    t = __builtin_amdgcn_cvt_pk_fp8_f32(acc[14][r], acc[15][r], t, 1);
    u.w = (unsigned)t;
    *(uint4*)&s_f8[wb + (quad * 4 + r) * 256 + am * 16] = u;
  }
#pragma unroll
  for (int p = 0; p < 4; p++) {
    uint4 u = *(const uint4*)&s_f8[wb + p * 1024 + lane * 16];
    *(uint4*)&xh8[(size_t)nb * 256 + p * 1024 + lane * 16] = u;
  }
}

// binA: 3072 edges/block, 12 edges/thread in registers (3x int4 coalesced
// loads for dst, 3x int4 for src); dst kept in regs across both passes.
__device__ __forceinline__ void binA_body(char* smem, int b,
                                          const int* __restrict__ ei,
                                          int* __restrict__ bucket_cnt,
                                          int2* __restrict__ ebuf) {
  int2* sorted = (int2*)smem;                         // 24576 B
  int*  hist   = (int*)(smem + 24576);                // 784 B
  int*  lbase  = (int*)(smem + 25360);                // 784 B
  int*  cur    = (int*)(smem + 26144);                // 784 B
  int*  runb   = (int*)(smem + 26928);                // 784 B
  int*  wsum   = (int*)(smem + 27712);                // 16 B
  int tid = threadIdx.x, lane = tid & 63, wid = tid >> 6;
  int e0 = b * EPB, e1 = min(e0 + EPB, NE);
  int n = e1 - e0;
  bool full = (e0 + EPB <= NE);

  int dd[12];
  if (full) {
#pragma unroll
    for (int r = 0; r < 3; r++) {
      int e = e0 + r * 1024 + tid * 4;
      int4 v = *(const int4*)&ei[NE + e];
      dd[r * 4 + 0] = v.x; dd[r * 4 + 1] = v.y;
      dd[r * 4 + 2] = v.z; dd[r * 4 + 3] = v.w;
    }
  } else {
#pragma unroll
    for (int r = 0; r < 3; r++)
#pragma unroll
      for (int k = 0; k < 4; k++) {
        int e = e0 + r * 1024 + tid * 4 + k;
        dd[r * 4 + k] = (e < e1) ? ei[NE + e] : -1;   // -1 = invalid sentinel
      }
  }
  if (tid < NB) hist[tid] = 0;
  __syncthreads();
#pragma unroll
  for (int q = 0; q < 12; q++)
    if (dd[q] >= 0) atomicAdd(&hist[dd[q] >> 8], 1);
  __syncthreads();
  {
    int v = (tid < NB) ? hist[tid] : 0;
    int s = v;
#pragma unroll
    for (int o = 1; o < 64; o <<= 1) { int t = __shfl_up(s, o, 64); if (lane >= o) s += t; }
    if (lane == 63) wsum[wid] = s;
    __syncthreads();
    int wbase = 0;
    for (int k = 0; k < wid; k++) wbase += wsum[k];
    if (tid < NB) {
      int ex = wbase + s - v;
      lbase[tid] = ex;
      cur[tid] = ex;
      runb[tid] = atomicAdd(&bucket_cnt[tid], v);
    }
  }
  __syncthreads();
  int ss[12];
  if (full) {
#pragma unroll
    for (int r = 0; r < 3; r++) {
      int e = e0 + r * 1024 + tid * 4;
      int4 v = *(const int4*)&ei[e];
      ss[r * 4 + 0] = v.x; ss[r * 4 + 1] = v.y;
      ss[r * 4 + 2] = v.z; ss[r * 4 + 3] = v.w;
    }
  } else {
#pragma unroll
    for (int r = 0; r < 3; r++)
#pragma unroll
      for (int k = 0; k < 4; k++) {
        int e = e0 + r * 1024 + tid * 4 + k;
        ss[r * 4 + k] = (e < e1) ? ei[e] : 0;
      }
  }
#pragma unroll
  for (int q = 0; q < 12; q++) {
    int d = dd[q];
    if (d >= 0) {
      int lp = atomicAdd(&cur[d >> 8], 1);
      sorted[lp] = make_int2(d, ss[q]);
    }
  }
  __syncthreads();
  for (int i = tid; i < n; i += 256) {
    int2 e = sorted[i];
    int bk = e.x >> 8;
    int slot = runb[bk] + (i - lbase[bk]);
    if (slot < CAP) ebuf[(size_t)bk * CAP + slot] = e;
  }
}

__global__ __launch_bounds__(256) void k_linbin(const float* __restrict__ x,
                                                const _Float16* __restrict__ wh,
                                                const _Float16* __restrict__ watt,
                                                unsigned char* __restrict__ xh8,
                                                float* __restrict__ a_src_n,
                                                float* __restrict__ a_dst_n,
                                                const int* __restrict__ ei,
                                                int* __restrict__ bucket_cnt,
                                                int2* __restrict__ ebuf) {
  __shared__ __align__(16) char smem[27744];
  if (blockIdx.x < NLINB)
    lin_body(smem, x, wh, watt, xh8, a_src_n, a_dst_n);
  else
    binA_body(smem, blockIdx.x - NLINB, ei, bucket_cnt, ebuf);
}

// ---------------- K2: per-bucket local hist+scan+scatter (inline bscan) -------
__global__ __launch_bounds__(256) void k_binB(const int2* __restrict__ ebuf,
                                              const int* __restrict__ bucket_cnt,
                                              int* __restrict__ deg,
                                              int* __restrict__ offs,
                                              int* __restrict__ src_list) {
  __shared__ int hist[256];
  __shared__ int cur[256];
  __shared__ int wsum[4];
  __shared__ int bbase[NB];
  int b = blockIdx.x, tid = threadIdx.x, lane = tid & 63, wid = tid >> 6;
  // inline scan of all bucket counts -> bbase
  {
    int v = (tid < NB) ? min(bucket_cnt[tid], CAP) : 0;
    int s = v;
#pragma unroll
    for (int o = 1; o < 64; o <<= 1) { int t = __shfl_up(s, o, 64); if (lane >= o) s += t; }
    if (lane == 63) wsum[wid] = s;
    __syncthreads();
    int wbase = 0;
    for (int k = 0; k < wid; k++) wbase += wsum[k];
    if (tid < NB) bbase[tid] = wbase + s - v;
  }
  __syncthreads();
  int cnt = min(bucket_cnt[b], CAP);
  int base = bbase[b];
  const int2* seg = ebuf + (size_t)b * CAP;
  hist[tid] = 0;
  __syncthreads();
  for (int i = tid; i < cnt; i += 256) atomicAdd(&hist[seg[i].x & 255], 1);
  __syncthreads();
  int v = hist[tid];
  int s = v;
#pragma unroll
  for (int o = 1; o < 64; o <<= 1) { int t = __shfl_up(s, o, 64); if (lane >= o) s += t; }
  if (lane == 63) wsum[wid] = s;
  __syncthreads();
  int wbase = 0;
  for (int k = 0; k < wid; k++) wbase += wsum[k];
  int excl = wbase + s - v;
  int node = b * 256 + tid;
  if (node < NN) {
    deg[node] = v;
    offs[node] = base + excl;
  }
  cur[tid] = excl;
  __syncthreads();
  for (int i = tid; i < cnt; i += 256) {
    int2 e = seg[i];
    int pos = base + atomicAdd(&cur[e.x & 255], 1);
    src_list[pos] = e.y;
  }
}

// ---------------- K3: GAT softmax + fp8 aggregation (dword gather, 8-deep) ----
__global__ __launch_bounds__(64) void k_gat(const unsigned char* __restrict__ xh8,
                                            const float* __restrict__ a_src_n,
                                            const float* __restrict__ a_dst_n,
                                            const int* __restrict__ offs,
                                            const int* __restrict__ deg_arr,
                                            const int* __restrict__ src_list,
                                            const float* __restrict__ gat_bias,
                                            __half* __restrict__ x2h,
                                            float* __restrict__ den_inv) {
  __shared__ __align__(16) float s_al[CHUNK * 4];
  __shared__ int s_src[CHUNK];
  __shared__ __half s_tr[256];
  int n = blockIdx.x, lane = threadIdx.x;
  int off = offs[n], dg = deg_arr[n], cnt = dg + 1;
  float4 ad = *(const float4*)&a_dst_n[n * 4];
  int h = lane & 3;
  unsigned loff = 4u * (unsigned)lane;   // 32-bit gather offsets (saddr form)
  float acc0 = 0.f, acc1 = 0.f, acc2 = 0.f, acc3 = 0.f;

  if (cnt <= 64) {
    float e0 = 0.f, e1 = 0.f, e2 = 0.f, e3 = 0.f;
    if (lane < cnt) {
      int src = (lane < dg) ? src_list[off + lane] : n;
      float4 as = *(const float4*)&a_src_n[src * 4];
      e0 = __expf(lrelu(as.x + ad.x));
      e1 = __expf(lrelu(as.y + ad.y));
      e2 = __expf(lrelu(as.z + ad.z));
      e3 = __expf(lrelu(as.w + ad.w));
      s_src[lane] = src;
    }
    float s0 = e0, s1 = e1, s2 = e2, s3 = e3;
#pragma unroll
    for (int o = 32; o >= 1; o >>= 1) {
      s0 += __shfl_xor(s0, o, 64);
      s1 += __shfl_xor(s1, o, 64);
      s2 += __shfl_xor(s2, o, 64);
      s3 += __shfl_xor(s3, o, 64);
    }
    float i0 = 1.f / (s0 + 1e-16f), i1 = 1.f / (s1 + 1e-16f);
    float i2 = 1.f / (s2 + 1e-16f), i3 = 1.f / (s3 + 1e-16f);
    if (lane == 0) *(float4*)&den_inv[n * 4] = make_float4(i0, i1, i2, i3);
    if (lane < cnt) {
      s_al[lane * 4 + 0] = e0 * i0;
      s_al[lane * 4 + 1] = e1 * i1;
      s_al[lane * 4 + 2] = e2 * i2;
      s_al[lane * 4 + 3] = e3 * i3;
    }
    __syncthreads();
    int j = 0;
    for (; j + 8 <= cnt; j += 8) {
      unsigned oA = ((unsigned)s_src[j + 0] << 8) + loff;
      unsigned oB = ((unsigned)s_src[j + 1] << 8) + loff;
      unsigned oC = ((unsigned)s_src[j + 2] << 8) + loff;
      unsigned oD = ((unsigned)s_src[j + 3] << 8) + loff;
      unsigned oE = ((unsigned)s_src[j + 4] << 8) + loff;
      unsigned oF = ((unsigned)s_src[j + 5] << 8) + loff;
      unsigned oG = ((unsigned)s_src[j + 6] << 8) + loff;
      unsigned oH = ((unsigned)s_src[j + 7] << 8) + loff;
      unsigned rA = *(const unsigned*)&xh8[oA];
      unsigned rB = *(const unsigned*)&xh8[oB];
      unsigned rC = *(const unsigned*)&xh8[oC];
      unsigned rD = *(const unsigned*)&xh8[oD];
      unsigned rE = *(const unsigned*)&xh8[oE];
      unsigned rF = *(const unsigned*)&xh8[oF];
      unsigned rG = *(const unsigned*)&xh8[oG];
      unsigned rH = *(const unsigned*)&xh8[oH];
      float aA = s_al[(j + 0) * 4 + h], aB = s_al[(j + 1) * 4 + h];
      float aC = s_al[(j + 2) * 4 + h], aD = s_al[(j + 3) * 4 + h];
      float aE = s_al[(j + 4) * 4 + h], aF = s_al[(j + 5) * 4 + h];
      float aG = s_al[(j + 6) * 4 + h], aH = s_al[(j + 7) * 4 + h];
      f32x2 p;
      p = __builtin_amdgcn_cvt_pk_f32_fp8((int)rA, 0); acc0 += aA * p[0]; acc1 += aA * p[1];
      p = __builtin_amdgcn_cvt_pk_f32_fp8((int)rA, 1); acc2 += aA * p[0]; acc3 += aA * p[1];
      p = __builtin_amdgcn_cvt_pk_f32_fp8((int)rB, 0); acc0 += aB * p[0]; acc1 += aB * p[1];
      p = __builtin_amdgcn_cvt_pk_f32_fp8((int)rB, 1); acc2 += aB * p[0]; acc3 += aB * p[1];
      p = __builtin_amdgcn_cvt_pk_f32_fp8((int)rC, 0); acc0 += aC * p[0]; acc1 += aC * p[1];
      p = __builtin_amdgcn_cvt_pk_f32_fp8((int)rC, 1); acc2 += aC * p[0]; acc3 += aC * p[1];
      p = __builtin_amdgcn_cvt_pk_f32_fp8((int)rD, 0); acc0 += aD * p[0]; acc1 += aD * p[1];
      p = __builtin_amdgcn_cvt_pk_f32_fp8((int)rD, 1); acc2 += aD * p[0]; acc3 += aD * p[1];
      p = __builtin_amdgcn_cvt_pk_f32_fp8((int)rE, 0); acc0 += aE * p[0]; acc1 += aE * p[1];
      p = __builtin_amdgcn_cvt_pk_f32_fp8((int)rE, 1); acc2 += aE * p[0]; acc3 += aE * p[1];
      p = __builtin_amdgcn_cvt_pk_f32_fp8((int)rF, 0); acc0 += aF * p[0]; acc1 += aF * p[1];
      p = __builtin_amdgcn_cvt_pk_f32_fp8((int)rF, 1); acc2 += aF * p[0]; acc3 += aF * p[1];
      p = __builtin_amdgcn_cvt_pk_f32_fp8((int)rG, 0); acc0 += aG * p[0]; acc1 += aG * p[1];
      p = __builtin_amdgcn_cvt_pk_f32_fp8((int)rG, 1); acc2 += aG * p[0]; acc3 += aG * p[1];
      p = __builtin_amdgcn_cvt_pk_f32_fp8((int)rH, 0); acc0 += aH * p[0]; acc1 += aH * p[1];
      p = __builtin_amdgcn_cvt_pk_f32_fp8((int)rH, 1); acc2 += aH * p[0]; acc3 += aH * p[1];
    }
    for (; j + 4 <= cnt; j += 4) {
      unsigned oA = ((unsigned)s_src[j] << 8) + loff;
      unsigned oB = ((unsigned)s_src[j + 1] << 8) + loff;
      unsigned oC = ((unsigned)s_src[j + 2] << 8) + loff;
      unsigned oD = ((unsigned)s_src[j + 3] << 8) + loff;
      unsigned rA = *(const unsigned*)&xh8[oA];
      unsigned rB = *(const unsigned*)&xh8[oB];
      unsigned rC = *(const unsigned*)&xh8[oC];
      unsigned rD = *(const unsigned*)&xh8[oD];
      float aA = s_al[j * 4 + h], aB = s_al[(j + 1) * 4 + h];
      float aC = s_al[(j + 2) * 4 + h], aD = s_al[(j + 3) * 4 + h];
      f32x2 p;
      p = __builtin_amdgcn_cvt_pk_f32_fp8((int)rA, 0); acc0 += aA * p[0]; acc1 += aA * p[1];
      p = __builtin_amdgcn_cvt_pk_f32_fp8((int)rA, 1); acc2 += aA * p[0]; acc3 += aA * p[1];
      p = __builtin_amdgcn_cvt_pk_f32_fp8((int)rB, 0); acc0 += aB * p[0]; acc1 += aB * p[1];
      p = __builtin_amdgcn_cvt_pk_f32_fp8((int)rB, 1); acc2 += aB * p[0]; acc3 += aB * p[1];
      p = __builtin_amdgcn_cvt_pk_f32_fp8((int)rC, 0); acc0 += aC * p[0]; acc1 += aC * p[1];
      p = __builtin_amdgcn_cvt_pk_f32_fp8((int)rC, 1); acc2 += aC * p[0]; acc3 += aC * p[1];
      p = __builtin_amdgcn_cvt_pk_f32_fp8((int)rD, 0); acc0 += aD * p[0]; acc1 += aD * p[1];
      p = __builtin_amdgcn_cvt_pk_f32_fp8((int)rD, 1); acc2 += aD * p[0]; acc3 += aD * p[1];
    }
    for (; j < cnt; j++) {
      unsigned oA = ((unsigned)s_src[j] << 8) + loff;
      unsigned rA = *(const unsigned*)&xh8[oA];
      float aA = s_al[j * 4 + h];
      f32x2 p;
      p = __builtin_amdgcn_cvt_pk_f32_fp8((int)rA, 0); acc0 += aA * p[0]; acc1 += aA * p[1];
      p = __builtin_amdgcn_cvt_pk_f32_fp8((int)rA, 1); acc2 += aA * p[0]; acc3 += aA * p[1];
    }
  } else {
    float s0 = 0.f, s1 = 0.f, s2 = 0.f, s3 = 0.f;
    for (int j = lane; j < cnt; j += 64) {
      int src = (j < dg) ? src_list[off + j] : n;
      float4 as = *(const float4*)&a_src_n[src * 4];
      s0 += __expf(lrelu(as.x + ad.x));
      s1 += __expf(lrelu(as.y + ad.y));
      s2 += __expf(lrelu(as.z + ad.z));
      s3 += __expf(lrelu(as.w + ad.w));
    }
#pragma unroll
    for (int o = 32; o >= 1; o >>= 1) {
      s0 += __shfl_xor(s0, o, 64);
      s1 += __shfl_xor(s1, o, 64);
      s2 += __shfl_xor(s2, o, 64);
      s3 += __shfl_xor(s3, o, 64);
    }
    float i0 = 1.f / (s0 + 1e-16f), i1 = 1.f / (s1 + 1e-16f);
    float i2 = 1.f / (s2 + 1e-16f), i3 = 1.f / (s3 + 1e-16f);
    if (lane == 0) *(float4*)&den_inv[n * 4] = make_float4(i0, i1, i2, i3);
    for (int cb = 0; cb < cnt; cb += CHUNK) {
      int clen = min(CHUNK, cnt - cb);
      for (int j = lane; j < clen; j += 64) {
        int jj = cb + j;
        int src = (jj < dg) ? src_list[off + jj] : n;
        float4 as = *(const float4*)&a_src_n[src * 4];
        s_src[j] = src;
        s_al[j * 4 + 0] = __expf(lrelu(as.x + ad.x)) * i0;
        s_al[j * 4 + 1] = __expf(lrelu(as.y + ad.y)) * i1;
        s_al[j * 4 + 2] = __expf(lrelu(as.z + ad.z)) * i2;
        s_al[j * 4 + 3] = __expf(lrelu(as.w + ad.w)) * i3;
      }
      __syncthreads();
      for (int j = 0; j < clen; j++) {
        unsigned oA = ((unsigned)s_src[j] << 8) + loff;
        unsigned rA = *(const unsigned*)&xh8[oA];
        float aA = s_al[j * 4 + h];
        f32x2 p;
        p = __builtin_amdgcn_cvt_pk_f32_fp8((int)rA, 0); acc0 += aA * p[0]; acc1 += aA * p[1];
        p = __builtin_amdgcn_cvt_pk_f32_fp8((int)rA, 1); acc2 += aA * p[0]; acc3 += aA * p[1];
      }
      __syncthreads();
    }
  }

  int cb0 = (lane & 3) * 64 + (lane >> 2);
  s_tr[cb0 +  0] = __float2half(acc0 + gat_bias[cb0 +  0]);
  s_tr[cb0 + 16] = __float2half(acc1 + gat_bias[cb0 + 16]);
  s_tr[cb0 + 32] = __float2half(acc2 + gat_bias[cb0 + 32]);
  s_tr[cb0 + 48] = __float2half(acc3 + gat_bias[cb0 + 48]);
  __syncthreads();
  uint2 u = *(const uint2*)&s_tr[4 * lane];
  *(uint2*)&x2h[(size_t)n * 256 + 4 * lane] = u;
}

// ---------------- K4: per-graph tail (LDS-staged, padded) + batched alpha ----
__global__ __launch_bounds__(256) void k_tail(const int* __restrict__ gcnt,
                                              const int* __restrict__ goff,
                                              const float* __restrict__ gn_w,
                                              const float* __restrict__ gn_b,
                                              const float* __restrict__ gn_ms,
                                              const __half* __restrict__ x2h,
                                              const _Float16* __restrict__ a1w,
                                              const float* __restrict__ att1_b,
                                              const float* __restrict__ att2_w,
                                              const float* __restrict__ att2_b,
                                              const float* __restrict__ fc1_w,
                                              const float* __restrict__ fc1_b,
                                              const float* __restrict__ out_w,
                                              const float* __restrict__ out_b,
                                              const int* __restrict__ ei,
                                              const float* __restrict__ a_src_n,
                                              const float* __restrict__ a_dst_n,
                                              const float* __restrict__ den_inv,
                                              float* __restrict__ alpha_out,
                                              float* __restrict__ outp) {
  __shared__ __align__(16) __half s_x[GLDS * SXP];   // ~147.8 KB, bank-padded
  __shared__ __align__(16) float s_sc[256];
  __shared__ __align__(16) float s_sh[256];
  __shared__ float s_gate[GMAX];          // exp(sigmoid(gate)) per local node
  __shared__ __align__(16) float pool_s[256];
  __shared__ float hred[128];
  __shared__ float red[4];
  int g = blockIdx.x, tid = threadIdx.x, lane = tid & 63, wid = tid >> 6;
  int cnt = gcnt[g], start = goff[g];
  int am = lane & 15, quad = lane >> 4;

  if (cnt <= GLDS) {
    // ---- pass 1: stats + stage into LDS (thread = channel) ----
    {
      int c = tid;
      const __half* p = x2h + (size_t)start * 256 + c;
      float S = 0.f, S2 = 0.f;
      int i = 0;
      for (; i + 7 < cnt; i += 8) {
        __half h0 = p[(size_t)(i + 0) * 256];
        __half h1 = p[(size_t)(i + 1) * 256];
        __half h2 = p[(size_t)(i + 2) * 256];
        __half h3 = p[(size_t)(i + 3) * 256];
        __half h4 = p[(size_t)(i + 4) * 256];
        __half h5 = p[(size_t)(i + 5) * 256];
        __half h6 = p[(size_t)(i + 6) * 256];
        __half h7 = p[(size_t)(i + 7) * 256];
        s_x[(i + 0) * SXP + c] = h0;
        s_x[(i + 1) * SXP + c] = h1;
        s_x[(i + 2) * SXP + c] = h2;
        s_x[(i + 3) * SXP + c] = h3;
        s_x[(i + 4) * SXP + c] = h4;
        s_x[(i + 5) * SXP + c] = h5;
        s_x[(i + 6) * SXP + c] = h6;
        s_x[(i + 7) * SXP + c] = h7;
        float v0 = __half2float(h0), v1 = __half2float(h1);
        float v2 = __half2float(h2), v3 = __half2float(h3);
        float v4 = __half2float(h4), v5 = __half2float(h5);
        float v6 = __half2float(h6), v7 = __half2float(h7);
        S  += ((v0 + v1) + (v2 + v3)) + ((v4 + v5) + (v6 + v7));
        S2 += ((v0 * v0 + v1 * v1) + (v2 * v2 + v3 * v3)) +
              ((v4 * v4 + v5 * v5) + (v6 * v6 + v7 * v7));
      }
      for (; i < cnt; i++) {
        __half hh = p[(size_t)i * 256];
        s_x[i * SXP + c] = hh;
        float v = __half2float(hh);
        S += v; S2 += v * v;
      }
      float fc = fmaxf((float)cnt, 1.f);
      float mean = S / fc;
      float mm = mean * gn_ms[c];
      float var = fmaxf(S2 / fc - 2.f * mm * mean + mm * mm, 0.f);
      float sc = gn_w[c] / sqrtf(var + GEPS);
      s_sc[c] = sc;
      s_sh[c] = gn_b[c] - sc * mm;
    }
    __syncthreads();

    // ---- gate MLP from LDS: 16 nodes / wave via MFMA ----
    float b1 = att1_b[am], w2 = att2_w[am], b2 = att2_b[0];
    const _Float16* bp = a1w + am * 256 + quad * 8;
    for (int i0 = wid * 16; i0 < cnt; i0 += 64) {
      int li = i0 + am;
      if (li > cnt - 1) li = cnt - 1;          // clamp (masked below)
      const __half* xp = &s_x[li * SXP + quad * 8];
      f32x4 ga = (f32x4){0.f, 0.f, 0.f, 0.f};
#pragma unroll
      for (int kb = 0; kb < 8; kb++) {
        f16x8 xv = *(const f16x8*)(xp + kb * 32);
        int cb = quad * 8 + kb * 32;
        float4 sc0 = *(const float4*)&s_sc[cb];
        float4 sc1 = *(const float4*)&s_sc[cb + 4];
        float4 sh0 = *(const float4*)&s_sh[cb];
        float4 sh1 = *(const float4*)&s_sh[cb + 4];
        f16x8 a;
        a[0] = (_Float16)fmaxf(sc0.x * (float)xv[0] + sh0.x, 0.f);
        a[1] = (_Float16)fmaxf(sc0.y * (float)xv[1] + sh0.y, 0.f);
        a[2] = (_Float16)fmaxf(sc0.z * (float)xv[2] + sh0.z, 0.f);
        a[3] = (_Float16)fmaxf(sc0.w * (float)xv[3] + sh0.w, 0.f);
        a[4] = (_Float16)fmaxf(sc1.x * (float)xv[4] + sh1.x, 0.f);
        a[5] = (_Float16)fmaxf(sc1.y * (float)xv[5] + sh1.y, 0.f);
        a[6] = (_Float16)fmaxf(sc1.z * (float)xv[6] + sh1.z, 0.f);
        a[7] = (_Float16)fmaxf(sc1.w * (float)xv[7] + sh1.w, 0.f);
        f16x8 b = *(const f16x8*)(bp + kb * 32);
        ga = __builtin_amdgcn_mfma_f32_16x16x32_f16(a, b, ga, 0, 0, 0);
      }
#pragma unroll
      for (int r = 0; r < 4; r++) {
        float t = w2 * fmaxf(ga[r] + b1, 0.f);
#pragma unroll
        for (int o = 1; o < 16; o <<= 1) t += __shfl_xor(t, o, 64);
        if (am == 0) {
          int li2 = i0 + quad * 4 + r;
          if (li2 < cnt) s_gate[li2] = __expf(1.f / (1.f + __expf(-(t + b2))));
        }
      }
    }
    __syncthreads();

    // ---- gate softmax denominator ----
    float ls = 0.f;
    for (int i = tid; i < cnt; i += 256) ls += s_gate[i];
#pragma unroll
    for (int o = 32; o >= 1; o >>= 1) ls += __shfl_xor(ls, o, 64);
    if (lane == 0) red[wid] = ls;
    __syncthreads();
    float rden = 1.f / (red[0] + red[1] + red[2] + red[3] + 1e-16f);

    // ---- weighted pool from LDS (thread = channel) ----
    {
      int c = tid;
      float sc = s_sc[c], sh = s_sh[c];
      float a0 = 0.f, a1_ = 0.f, a2 = 0.f, a3 = 0.f;
      float a4 = 0.f, a5 = 0.f, a6 = 0.f, a7 = 0.f;
      int i = 0;
      for (; i + 7 < cnt; i += 8) {
        float v0 = __half2float(s_x[(i + 0) * SXP + c]);
        float v1 = __half2float(s_x[(i + 1) * SXP + c]);
        float v2 = __half2float(s_x[(i + 2) * SXP + c]);
        float v3 = __half2float(s_x[(i + 3) * SXP + c]);
        float v4 = __half2float(s_x[(i + 4) * SXP + c]);
        float v5 = __half2float(s_x[(i + 5) * SXP + c]);
        float v6 = __half2float(s_x[(i + 6) * SXP + c]);
        float v7 = __half2float(s_x[(i + 7) * SXP + c]);
        a0 += s_gate[i + 0] * fmaxf(sc * v0 + sh, 0.f);
        a1_ += s_gate[i + 1] * fmaxf(sc * v1 + sh, 0.f);
        a2 += s_gate[i + 2] * fmaxf(sc * v2 + sh, 0.f);
        a3 += s_gate[i + 3] * fmaxf(sc * v3 + sh, 0.f);
        a4 += s_gate[i + 4] * fmaxf(sc * v4 + sh, 0.f);
        a5 += s_gate[i + 5] * fmaxf(sc * v5 + sh, 0.f);
        a6 += s_gate[i + 6] * fmaxf(sc * v6 + sh, 0.f);
        a7 += s_gate[i + 7] * fmaxf(sc * v7 + sh, 0.f);
      }
      for (; i < cnt; i++)
        a0 += s_gate[i] * fmaxf(sc * __half2float(s_x[i * SXP + c]) + sh, 0.f);
      pool_s[c] = ((((a0 + a1_) + (a2 + a3)) + ((a4 + a5) + (a6 + a7)))) * rden;
    }
  } else {
    // ---- fallback: original 3-pass global path (cnt > GLDS, ~never) ----
    {
      int c = tid;
      const __half* p = x2h + (size_t)start * 256 + c;
      float S = 0.f, S2 = 0.f;
      int i = 0;
      for (; i + 7 < cnt; i += 8) {
        float v0 = __half2float(p[(size_t)(i + 0) * 256]);
        float v1 = __half2float(p[(size_t)(i + 1) * 256]);
        float v2 = __half2float(p[(size_t)(i + 2) * 256]);
        float v3 = __half2float(p[(size_t)(i + 3) * 256]);
        float v4 = __half2float(p[(size_t)(i + 4) * 256]);
        float v5 = __half2float(p[(size_t)(i + 5) * 256]);
        float v6 = __half2float(p[(size_t)(i + 6) * 256]);
        float v7 = __half2float(p[(size_t)(i + 7) * 256]);
        S  += ((v0 + v1) + (v2 + v3)) + ((v4 + v5) + (v6 + v7));
        S2 += ((v0 * v0 + v1 * v1) + (v2 * v2 + v3 * v3)) +
              ((v4 * v4 + v5 * v5) + (v6 * v6 + v7 * v7));
      }
      for (; i < cnt; i++) { float v = __half2float(p[(size_t)i * 256]); S += v; S2 += v * v; }
      float fc = fmaxf((float)cnt, 1.f);
      float mean = S / fc;
      float mm = mean * gn_ms[c];
      float var = fmaxf(S2 / fc - 2.f * mm * mean + mm * mm, 0.f);
      float sc = gn_w[c] / sqrtf(var + GEPS);
      s_sc[c] = sc;
      s_sh[c] = gn_b[c] - sc * mm;
    }
    __syncthreads();

    float b1 = att1_b[am], w2 = att2_w[am], b2 = att2_b[0];
    const _Float16* bp = a1w + am * 256 + quad * 8;
    for (int i0 = wid * 16; i0 < cnt; i0 += 64) {
      int node = start + i0 + am;
      if (node > NN - 1) node = NN - 1;
      const __half* xp = x2h + (size_t)node * 256 + quad * 8;
      f32x4 ga = (f32x4){0.f, 0.f, 0.f, 0.f};
#pragma unroll
      for (int kb = 0; kb < 8; kb++) {
        f16x8 xv = *(const f16x8*)(xp + kb * 32);
        int cb = quad * 8 + kb * 32;
        float4 sc0 = *(const float4*)&s_sc[cb];
        float4 sc1 = *(const float4*)&s_sc[cb + 4];
        float4 sh0 = *(const float4*)&s_sh[cb];
        float4 sh1 = *(const float4*)&s_sh[cb + 4];
        f16x8 a;
        a[0] = (_Float16)fmaxf(sc0.x * (float)xv[0] + sh0.x, 0.f);
        a[1] = (_Float16)fmaxf(sc0.y * (float)xv[1] + sh0.y, 0.f);
        a[2] = (_Float16)fmaxf(sc0.z * (float)xv[2] + sh0.z, 0.f);
        a[3] = (_Float16)fmaxf(sc0.w * (float)xv[3] + sh0.w, 0.f);
        a[4] = (_Float16)fmaxf(sc1.x * (float)xv[4] + sh1.x, 0.f);
        a[5] = (_Float16)fmaxf(sc1.y * (float)xv[5] + sh1.y, 0.f);
        a[6] = (_Float16)fmaxf(sc1.z * (float)xv[6] + sh1.z, 0.f);
        a[7] = (_Float16)fmaxf(sc1.w * (float)xv[7] + sh1.w, 0.f);
        f16x8 b = *(const f16x8*)(bp + kb * 32);
        ga = __builtin_amdgcn_mfma_f32_16x16x32_f16(a, b, ga, 0, 0, 0);
      }
#pragma unroll
      for (int r = 0; r < 4; r++) {
        float t = w2 * fmaxf(ga[r] + b1, 0.f);
#pragma unroll
        for (int o = 1; o < 16; o <<= 1) t += __shfl_xor(t, o, 64);
        if (am == 0) {
          int li = i0 + quad * 4 + r;
          if (li < cnt && li < GMAX)
            s_gate[li] = __expf(1.f / (1.f + __expf(-(t + b2))));
        }
      }
    }
    __syncthreads();

    float ls = 0.f;
    for (int i = tid; i < cnt; i += 256) ls += (i < GMAX) ? s_gate[i] : 0.f;
#pragma unroll
    for (int o = 32; o >= 1; o >>= 1) ls += __shfl_xor(ls, o, 64);
    if (lane == 0) red[wid] = ls;
    __syncthreads();
    float rden = 1.f / (red[0] + red[1] + red[2] + red[3] + 1e-16f);

    {
      int c = tid;
      float sc = s_sc[c], sh = s_sh[c];
      const __half* p = x2h + (size_t)start * 256 + c;
      float a0 = 0.f;
      for (int i = 0; i < cnt; i++) {
        float w = (i < GMAX) ? s_gate[i] : 0.f;
        a0 += w * fmaxf(sc * __half2float(p[(size_t)i * 256]) + sh, 0.f);
      }
      pool_s[c] = a0 * rden;
    }
  }
  __syncthreads();

  // ---- fc1 + out head (common) ----
  float4 psv = *(const float4*)&pool_s[4 * lane];
  for (int j0 = 0; j0 < 32; j0++) {
    int j = wid * 32 + j0;
    float4 w = *(const float4*)&fc1_w[j * 256 + 4 * lane];
    float d = w.x * psv.x + w.y * psv.y + w.z * psv.z + w.w * psv.w;
#pragma unroll
    for (int o = 32; o >= 1; o >>= 1) d += __shfl_xor(d, o, 64);
    if (lane == 0) hred[j] = fmaxf(d + fc1_b[j], 0.f) * out_w[j];
  }
  __syncthreads();
  if (tid < 128) {
    float v = hred[tid];
#pragma unroll
    for (int o = 32; o >= 1; o >>= 1) v += __shfl_xor(v, o, 64);
    if (lane == 0) red[wid] = v;
  }
  __syncthreads();
  if (tid == 0) outp[g] = 1.f / (1.f + __expf(-(red[0] + red[1] + out_b[0])));

  // ---- alpha edge slab: 4 edges in flight per thread (batched loads) --------
  {
    int base = g * EPT;
    int end = min(base + EPT, NE + NN);
    int idx = base + tid;
    for (; idx + 768 < end; idx += 1024) {
      int i0 = idx, i1 = idx + 256, i2 = idx + 512, i3 = idx + 768;
      int s0, d0, s1, d1, s2, d2, s3, d3;
      if (i0 < NE) { s0 = ei[i0]; d0 = ei[NE + i0]; } else { s0 = i0 - NE; d0 = s0; }
      if (i1 < NE) { s1 = ei[i1]; d1 = ei[NE + i1]; } else { s1 = i1 - NE; d1 = s1; }
      if (i2 < NE) { s2 = ei[i2]; d2 = ei[NE + i2]; } else { s2 = i2 - NE; d2 = s2; }
      if (i3 < NE) { s3 = ei[i3]; d3 = ei[NE + i3]; } else { s3 = i3 - NE; d3 = s3; }
      float4 as0 = *(const float4*)&a_src_n[s0 * 4];
      float4 ad0 = *(const float4*)&a_dst_n[d0 * 4];
      float4 iv0 = *(const float4*)&den_inv[d0 * 4];
      float4 as1 = *(const float4*)&a_src_n[s1 * 4];
      float4 ad1 = *(const float4*)&a_dst_n[d1 * 4];
      float4 iv1 = *(const float4*)&den_inv[d1 * 4];
      float4 as2 = *(const float4*)&a_src_n[s2 * 4];
      float4 ad2 = *(const float4*)&a_dst_n[d2 * 4];
      float4 iv2 = *(const float4*)&den_inv[d2 * 4];
      float4 as3 = *(const float4*)&a_src_n[s3 * 4];
      float4 ad3 = *(const float4*)&a_dst_n[d3 * 4];
      float4 iv3 = *(const float4*)&den_inv[d3 * 4];
      float4 a;
      a.x = __expf(lrelu(as0.x + ad0.x)) * iv0.x;
      a.y = __expf(lrelu(as0.y + ad0.y)) * iv0.y;
      a.z = __expf(lrelu(as0.z + ad0.z)) * iv0.z;
      a.w = __expf(lrelu(as0.w + ad0.w)) * iv0.w;
      *(float4*)&alpha_out[(size_t)i0 * 4] = a;
      a.x = __expf(lrelu(as1.x + ad1.x)) * iv1.x;
      a.y = __expf(lrelu(as1.y + ad1.y)) * iv1.y;
      a.z = __expf(lrelu(as1.z + ad1.z)) * iv1.z;
      a.w = __expf(lrelu(as1.w + ad1.w)) * iv1.w;
      *(float4*)&alpha_out[(size_t)i1 * 4] = a;
      a.x = __expf(lrelu(as2.x + ad2.x)) * iv2.x;
      a.y = __expf(lrelu(as2.y + ad2.y)) * iv2.y;
      a.z = __expf(lrelu(as2.z + ad2.z)) * iv2.z;
      a.w = __expf(lrelu(as2.w + ad2.w)) * iv2.w;
      *(float4*)&alpha_out[(size_t)i2 * 4] = a;
      a.x = __expf(lrelu(as3.x + ad3.x)) * iv3.x;
      a.y = __expf(lrelu(as3.y + ad3.y)) * iv3.y;
      a.z = __expf(lrelu(as3.z + ad3.z)) * iv3.z;
      a.w = __expf(lrelu(as3.w + ad3.w)) * iv3.w;
      *(float4*)&alpha_out[(size_t)i3 * 4] = a;
    }
    for (; idx < end; idx += 256) {
      int s, d;
      if (idx < NE) { s = ei[idx]; d = ei[NE + idx]; }
      else          { s = idx - NE; d = s; }
      float4 as = *(const float4*)&a_src_n[s * 4];
      float4 ad = *(const float4*)&a_dst_n[d * 4];
      float4 iv = *(const float4*)&den_inv[d * 4];
      float4 a;
      a.x = __expf(lrelu(as.x + ad.x)) * iv.x;
      a.y = __expf(lrelu(as.y + ad.y)) * iv.y;
      a.z = __expf(lrelu(as.z + ad.z)) * iv.z;
      a.w = __expf(lrelu(as.w + ad.w)) * iv.w;
      *(float4*)&alpha_out[(size_t)idx * 4] = a;
    }
  }
}

// -----------------------------------------------------------------------------
extern "C" void kernel_launch(void* const* d_in, const int* in_sizes, int n_in,
                              void* d_out, int out_size, void* d_ws, size_t ws_size,
                              hipStream_t stream) {
  const float* x        = (const float*)d_in[0];
  const int*   ei       = (const int*)d_in[1];
  const int*   batch    = (const int*)d_in[2];
  const float* lin_w    = (const float*)d_in[3];
  const float* att_src  = (const float*)d_in[4];
  const float* att_dst  = (const float*)d_in[5];
  const float* gat_bias = (const float*)d_in[6];
  const float* gn_w     = (const float*)d_in[7];
  const float* gn_b     = (const float*)d_in[8];
  const float* gn_ms    = (const float*)d_in[9];
  const float* fc1_w    = (const float*)d_in[10];
  const float* fc1_b    = (const float*)d_in[11];
  const float* out_w    = (const float*)d_in[12];
  const float* out_b    = (const float*)d_in[13];
  const float* att1_w   = (const float*)d_in[14];
  const float* att1_b   = (const float*)d_in[15];
  const float* att2_w   = (const float*)d_in[16];
  const float* att2_b   = (const float*)d_in[17];

  float* outp  = (float*)d_out;       // [256]
  float* alpha = outp + NG;           // [(E+N)*4]

  char* wsb = (char*)d_ws;
  size_t o = 0;
  auto A = [&](size_t bytes) -> char* {
    char* p = wsb + o;
    o += (bytes + 255) & ~(size_t)255;
    return p;
  };
  unsigned char* xh8 = (unsigned char*)A((size_t)NN * 256);
  __half*   x2h      = (__half*)A((size_t)NN * 256 * 2);
  _Float16* wh       = (_Float16*)A((size_t)256 * 64 * 2);
  _Float16* a1w      = (_Float16*)A((size_t)16 * 256 * 2);
  _Float16* watt     = (_Float16*)A((size_t)16 * 64 * 2);
  float* a_src_n  = (float*)A((size_t)NN * 4 * 4);
  float* a_dst_n  = (float*)A((size_t)NN * 4 * 4);
  float* den_inv  = (float*)A((size_t)NN * 4 * 4);
  int*   deg      = (int*)A((size_t)NN * 4);
  int*   gcnt     = (int*)A((size_t)NG * 4);
  int*   offs     = (int*)A((size_t)NN * 4);
  int*   goff     = (int*)A((size_t)NG * 4);
  int*   src_list = (int*)A((size_t)NE * 4);
  int2*  ebuf     = (int2*)A((size_t)NB * CAP * 8);
  int*   bucket_cnt  = (int*)A((size_t)NB * 4);

  k_misc<<<22, 256, 0, stream>>>(lin_w, wh, att1_w, a1w, att_src, att_dst, watt,
                                 batch, goff, gcnt, bucket_cnt);
  k_linbin<<<NLINB + NAB, 256, 0, stream>>>(x, wh, watt, xh8, a_src_n, a_dst_n,
                                            ei, bucket_cnt, ebuf);
  k_binB<<<NB, 256, 0, stream>>>(ebuf, bucket_cnt, deg, offs, src_list);
  k_gat<<<NN, 64, 0, stream>>>(xh8, a_src_n, a_dst_n, offs, deg, src_list,
                               gat_bias, x2h, den_inv);
  k_tail<<<NG, 256, 0, stream>>>(gcnt, goff, gn_w, gn_b, gn_ms, x2h,
                                 a1w, att1_b, att2_w, att2_b, fc1_w, fc1_b,
                                 out_w, out_b, ei, a_src_n, a_dst_n, den_inv,
                                 alpha, outp);
}

// Round 14
// 220.474 us; speedup vs baseline: 1.0213x; 1.0213x over previous
//
#include <hip/hip_runtime.h>
#include <hip/hip_fp16.h>
#include <math.h>

#define NN 50000
#define NE 800000
#define NG 256
#define NEG_SLOPE 0.2f
#define GEPS 1e-5f
#define CHUNK 64
#define NB 196          // coarse buckets of 256 node-ids (dst >> 8)
#define CAP 6144        // per-bucket segment capacity (mean 4081)
#define NAB 261         // binA blocks = ceil(NE/EPB)
#define EPB 3072        // edges per binA block (12/thread, int4-aligned)
#define NLINB 782       // (NN+63)/64 lin blocks
#define EPT 3321        // alpha edges per tail block = ceil((NE+NN)/NG)
#define GMAX 512        // fallback gate capacity
#define GLDS 280        // staged rows per graph (actual max ~240)
#define SXP 264         // padded s_x row stride in halves (528 B -> bank-safe)

typedef _Float16 f16x8 __attribute__((ext_vector_type(8)));
typedef _Float16 f16x4 __attribute__((ext_vector_type(4)));
typedef float f32x4 __attribute__((ext_vector_type(4)));
typedef float f32x2 __attribute__((ext_vector_type(2)));

__device__ __forceinline__ float lrelu(float v){ return v > 0.f ? v : NEG_SLOPE * v; }

// ---------------- K0: weight converts + goff + bucket zero + w_att build -----
__global__ __launch_bounds__(256) void k_misc(const float* __restrict__ lin_w,
                                              _Float16* __restrict__ wh,
                                              const float* __restrict__ att1_w,
                                              _Float16* __restrict__ a1w,
                                              const float* __restrict__ att_src,
                                              const float* __restrict__ att_dst,
                                              _Float16* __restrict__ watt,
                                              const int* __restrict__ batch,
                                              int* __restrict__ goff,
                                              int* __restrict__ gcnt,
                                              int* __restrict__ bucket_cnt) {
  int b = blockIdx.x, tid = threadIdx.x;
  if (b == 0) {
    if (tid < NB) bucket_cnt[tid] = 0;
    int g = tid;
    int lo = 0, hi = NN;
    while (lo < hi) { int mid = (lo + hi) >> 1; if (batch[mid] < g) lo = mid + 1; else hi = mid; }
    int start = lo;
    lo = 0; hi = NN;
    while (lo < hi) { int mid = (lo + hi) >> 1; if (batch[mid] < g + 1) lo = mid + 1; else hi = mid; }
    goff[g] = start;
    gcnt[g] = lo - start;
  } else if (b <= 16) {
    int i0 = (b - 1) * 1024 + tid * 4;
    float4 f = *(const float4*)&lin_w[i0];
    f16x4 h4;
    h4[0] = (_Float16)f.x; h4[1] = (_Float16)f.y; h4[2] = (_Float16)f.z; h4[3] = (_Float16)f.w;
    *(f16x4*)&wh[i0] = h4;
  } else if (b <= 20) {
    int i0 = (b - 17) * 1024 + tid * 4;
    float4 f = *(const float4*)&att1_w[i0];
    f16x4 h4;
    h4[0] = (_Float16)f.x; h4[1] = (_Float16)f.y; h4[2] = (_Float16)f.z; h4[3] = (_Float16)f.w;
    *(f16x4*)&a1w[i0] = h4;
  } else {
    for (int e = tid; e < 16 * 64; e += 256) {
      int row = e >> 6, k = e & 63;
      float s = 0.f;
      if (row < 8) {
        int h = row & 3;
        const float* av = (row < 4) ? att_src : att_dst;
        for (int c = 0; c < 64; c++)
          s += av[h * 64 + c] * lin_w[(h * 64 + c) * 64 + k];
      }
      watt[e] = (_Float16)s;
    }
  }
}

// ---------------- K1 fused: MFMA lin (blocks < NLINB) | binA sort (rest) ------
__device__ __forceinline__ void lin_body(char* smem,
                                         const float* __restrict__ x,
                                         const _Float16* __restrict__ wh,
                                         const _Float16* __restrict__ watt,
                                         unsigned char* __restrict__ xh8,
                                         float* __restrict__ a_src_n,
                                         float* __restrict__ a_dst_n) {
  unsigned char* s_f8 = (unsigned char*)smem;     // 16 KB (4 waves x 4 KB)
  int w = threadIdx.x >> 6, lane = threadIdx.x & 63;
  int nb = blockIdx.x * 64 + w * 16;
  if (nb >= NN) return;                 // per-wave LDS region; no barriers used
  int am = lane & 15, quad = lane >> 4;
  int wb = w * 4096;

  const float* xr = x + (size_t)(nb + am) * 64 + quad * 8;
  float4 f0 = *(const float4*)(xr);
  float4 f1 = *(const float4*)(xr + 4);
  float4 f2 = *(const float4*)(xr + 32);
  float4 f3 = *(const float4*)(xr + 36);
  f16x8 a0, a1;
  a0[0] = (_Float16)f0.x; a0[1] = (_Float16)f0.y; a0[2] = (_Float16)f0.z; a0[3] = (_Float16)f0.w;
  a0[4] = (_Float16)f1.x; a0[5] = (_Float16)f1.y; a0[6] = (_Float16)f1.z; a0[7] = (_Float16)f1.w;
  a1[0] = (_Float16)f2.x; a1[1] = (_Float16)f2.y; a1[2] = (_Float16)f2.z; a1[3] = (_Float16)f2.w;
  a1[4] = (_Float16)f3.x; a1[5] = (_Float16)f3.y; a1[6] = (_Float16)f3.z; a1[7] = (_Float16)f3.w;

  f32x4 acc[16];
#pragma unroll
  for (int ct = 0; ct < 16; ct++) acc[ct] = (f32x4){0.f, 0.f, 0.f, 0.f};

#pragma unroll
  for (int ct = 0; ct < 16; ct++) {
    const _Float16* wbp = wh + (size_t)(ct * 16 + am) * 64 + quad * 8;
    f16x8 b0 = *(const f16x8*)(wbp);
    f16x8 b1 = *(const f16x8*)(wbp + 32);
    acc[ct] = __builtin_amdgcn_mfma_f32_16x16x32_f16(a0, b0, acc[ct], 0, 0, 0);
    acc[ct] = __builtin_amdgcn_mfma_f32_16x16x32_f16(a1, b1, acc[ct], 0, 0, 0);
  }

  // attention projections via one extra MFMA pair (replaces 128-shfl reduce)
  {
    const _Float16* wap = watt + am * 64 + quad * 8;
    f16x8 t0 = *(const f16x8*)(wap);
    f16x8 t1 = *(const f16x8*)(wap + 32);
    f32x4 acca = (f32x4){0.f, 0.f, 0.f, 0.f};
    acca = __builtin_amdgcn_mfma_f32_16x16x32_f16(a0, t0, acca, 0, 0, 0);
    acca = __builtin_amdgcn_mfma_f32_16x16x32_f16(a1, t1, acca, 0, 0, 0);
    if (am < 8) {
#pragma unroll
      for (int r = 0; r < 4; r++) {
        int node = nb + quad * 4 + r;
        if (am < 4) a_src_n[node * 4 + am] = acca[r];
        else        a_dst_n[node * 4 + (am - 4)] = acca[r];
      }
    }
  }

#pragma unroll
  for (int r = 0; r < 4; r++) {
    uint4 u;
    int t;
    t = __builtin_amdgcn_cvt_pk_fp8_f32(acc[0][r],  acc[1][r],  0, 0);
    t = __builtin_amdgcn_cvt_pk_fp8_f32(acc[2][r],  acc[3][r],  t, 1);
    u.x = (unsigned)t;
    t = __builtin_amdgcn_cvt_pk_fp8_f32(acc[4][r],  acc[5][r],  0, 0);
    t = __builtin_amdgcn_cvt_pk_fp8_f32(acc[6][r],  acc[7][r],  t, 1);
    u.y = (unsigned)t;
    t = __builtin_amdgcn_cvt_pk_fp8_f32(acc[8][r],  acc[9][r],  0, 0);
    t = __builtin_amdgcn_cvt_pk_fp8_f32(acc[10][r], acc[11][r], t, 1);
    u.z = (unsigned)t;
    t = __builtin_amdgcn_cvt_pk_fp8_f32(acc[12][r], acc[13][r], 0, 0);
    t = __builtin_amdgcn_cvt_pk_fp8_f32(acc[14][r], acc[15][r], t, 1);
    u.w = (unsigned)t;
    *(uint4*)&s_f8[wb + (quad * 4 + r) * 256 + am * 16] = u;
  }
#pragma unroll
  for (int p = 0; p < 4; p++) {
    uint4 u = *(const uint4*)&s_f8[wb + p * 1024 + lane * 16];
    *(uint4*)&xh8[(size_t)nb * 256 + p * 1024 + lane * 16] = u;
  }
}

// binA: 3072 edges/block, 12 edges/thread in registers (3x int4 coalesced
// loads for dst, 3x int4 for src); dst kept in regs across both passes.
__device__ __forceinline__ void binA_body(char* smem, int b,
                                          const int* __restrict__ ei,
                                          int* __restrict__ bucket_cnt,
                                          int2* __restrict__ ebuf) {
  int2* sorted = (int2*)smem;                         // 24576 B
  int*  hist   = (int*)(smem + 24576);                // 784 B
  int*  lbase  = (int*)(smem + 25360);                // 784 B
  int*  cur    = (int*)(smem + 26144);                // 784 B
  int*  runb   = (int*)(smem + 26928);                // 784 B
  int*  wsum   = (int*)(smem + 27712);                // 16 B
  int tid = threadIdx.x, lane = tid & 63, wid = tid >> 6;
  int e0 = b * EPB, e1 = min(e0 + EPB, NE);
  int n = e1 - e0;
  bool full = (e0 + EPB <= NE);

  int dd[12];
  if (full) {
#pragma unroll
    for (int r = 0; r < 3; r++) {
      int e = e0 + r * 1024 + tid * 4;
      int4 v = *(const int4*)&ei[NE + e];
      dd[r * 4 + 0] = v.x; dd[r * 4 + 1] = v.y;
      dd[r * 4 + 2] = v.z; dd[r * 4 + 3] = v.w;
    }
  } else {
#pragma unroll
    for (int r = 0; r < 3; r++)
#pragma unroll
      for (int k = 0; k < 4; k++) {
        int e = e0 + r * 1024 + tid * 4 + k;
        dd[r * 4 + k] = (e < e1) ? ei[NE + e] : -1;   // -1 = invalid sentinel
      }
  }
  if (tid < NB) hist[tid] = 0;
  __syncthreads();
#pragma unroll
  for (int q = 0; q < 12; q++)
    if (dd[q] >= 0) atomicAdd(&hist[dd[q] >> 8], 1);
  __syncthreads();
  {
    int v = (tid < NB) ? hist[tid] : 0;
    int s = v;
#pragma unroll
    for (int o = 1; o < 64; o <<= 1) { int t = __shfl_up(s, o, 64); if (lane >= o) s += t; }
    if (lane == 63) wsum[wid] = s;
    __syncthreads();
    int wbase = 0;
    for (int k = 0; k < wid; k++) wbase += wsum[k];
    if (tid < NB) {
      int ex = wbase + s - v;
      lbase[tid] = ex;
      cur[tid] = ex;
      runb[tid] = atomicAdd(&bucket_cnt[tid], v);
    }
  }
  __syncthreads();
  int ss[12];
  if (full) {
#pragma unroll
    for (int r = 0; r < 3; r++) {
      int e = e0 + r * 1024 + tid * 4;
      int4 v = *(const int4*)&ei[e];
      ss[r * 4 + 0] = v.x; ss[r * 4 + 1] = v.y;
      ss[r * 4 + 2] = v.z; ss[r * 4 + 3] = v.w;
    }
  } else {
#pragma unroll
    for (int r = 0; r < 3; r++)
#pragma unroll
      for (int k = 0; k < 4; k++) {
        int e = e0 + r * 1024 + tid * 4 + k;
        ss[r * 4 + k] = (e < e1) ? ei[e] : 0;
      }
  }
#pragma unroll
  for (int q = 0; q < 12; q++) {
    int d = dd[q];
    if (d >= 0) {
      int lp = atomicAdd(&cur[d >> 8], 1);
      sorted[lp] = make_int2(d, ss[q]);
    }
  }
  __syncthreads();
  for (int i = tid; i < n; i += 256) {
    int2 e = sorted[i];
    int bk = e.x >> 8;
    int slot = runb[bk] + (i - lbase[bk]);
    if (slot < CAP) ebuf[(size_t)bk * CAP + slot] = e;
  }
}

__global__ __launch_bounds__(256) void k_linbin(const float* __restrict__ x,
                                                const _Float16* __restrict__ wh,
                                                const _Float16* __restrict__ watt,
                                                unsigned char* __restrict__ xh8,
                                                float* __restrict__ a_src_n,
                                                float* __restrict__ a_dst_n,
                                                const int* __restrict__ ei,
                                                int* __restrict__ bucket_cnt,
                                                int2* __restrict__ ebuf) {
  __shared__ __align__(16) char smem[27744];
  if (blockIdx.x < NLINB)
    lin_body(smem, x, wh, watt, xh8, a_src_n, a_dst_n);
  else
    binA_body(smem, blockIdx.x - NLINB, ei, bucket_cnt, ebuf);
}

// ---------------- K2: per-bucket local hist+scan+scatter (inline bscan) -------
__global__ __launch_bounds__(256) void k_binB(const int2* __restrict__ ebuf,
                                              const int* __restrict__ bucket_cnt,
                                              int* __restrict__ deg,
                                              int* __restrict__ offs,
                                              int* __restrict__ src_list) {
  __shared__ int hist[256];
  __shared__ int cur[256];
  __shared__ int wsum[4];
  __shared__ int bbase[NB];
  int b = blockIdx.x, tid = threadIdx.x, lane = tid & 63, wid = tid >> 6;
  // inline scan of all bucket counts -> bbase
  {
    int v = (tid < NB) ? min(bucket_cnt[tid], CAP) : 0;
    int s = v;
#pragma unroll
    for (int o = 1; o < 64; o <<= 1) { int t = __shfl_up(s, o, 64); if (lane >= o) s += t; }
    if (lane == 63) wsum[wid] = s;
    __syncthreads();
    int wbase = 0;
    for (int k = 0; k < wid; k++) wbase += wsum[k];
    if (tid < NB) bbase[tid] = wbase + s - v;
  }
  __syncthreads();
  int cnt = min(bucket_cnt[b], CAP);
  int base = bbase[b];
  const int2* seg = ebuf + (size_t)b * CAP;
  hist[tid] = 0;
  __syncthreads();
  for (int i = tid; i < cnt; i += 256) atomicAdd(&hist[seg[i].x & 255], 1);
  __syncthreads();
  int v = hist[tid];
  int s = v;
#pragma unroll
  for (int o = 1; o < 64; o <<= 1) { int t = __shfl_up(s, o, 64); if (lane >= o) s += t; }
  if (lane == 63) wsum[wid] = s;
  __syncthreads();
  int wbase = 0;
  for (int k = 0; k < wid; k++) wbase += wsum[k];
  int excl = wbase + s - v;
  int node = b * 256 + tid;
  if (node < NN) {
    deg[node] = v;
    offs[node] = base + excl;
  }
  cur[tid] = excl;
  __syncthreads();
  for (int i = tid; i < cnt; i += 256) {
    int2 e = seg[i];
    int pos = base + atomicAdd(&cur[e.x & 255], 1);
    src_list[pos] = e.y;
  }
}

// ---------------- K3: GAT softmax + fp8 aggregation (dword gather, 8-deep) ----
__global__ __launch_bounds__(64) void k_gat(const unsigned char* __restrict__ xh8,
                                            const float* __restrict__ a_src_n,
                                            const float* __restrict__ a_dst_n,
                                            const int* __restrict__ offs,
                                            const int* __restrict__ deg_arr,
                                            const int* __restrict__ src_list,
                                            const float* __restrict__ gat_bias,
                                            __half* __restrict__ x2h,
                                            float* __restrict__ den_inv) {
  __shared__ __align__(16) float s_al[CHUNK * 4];
  __shared__ int s_src[CHUNK];
  __shared__ __half s_tr[256];
  int n = blockIdx.x, lane = threadIdx.x;
  int off = offs[n], dg = deg_arr[n], cnt = dg + 1;
  float4 ad = *(const float4*)&a_dst_n[n * 4];
  int h = lane & 3;
  unsigned loff = 4u * (unsigned)lane;   // 32-bit gather offsets (saddr form)
  float acc0 = 0.f, acc1 = 0.f, acc2 = 0.f, acc3 = 0.f;

  if (cnt <= 64) {
    float e0 = 0.f, e1 = 0.f, e2 = 0.f, e3 = 0.f;
    if (lane < cnt) {
      int src = (lane < dg) ? src_list[off + lane] : n;
      float4 as = *(const float4*)&a_src_n[src * 4];
      e0 = __expf(lrelu(as.x + ad.x));
      e1 = __expf(lrelu(as.y + ad.y));
      e2 = __expf(lrelu(as.z + ad.z));
      e3 = __expf(lrelu(as.w + ad.w));
      s_src[lane] = src;
    }
    float s0 = e0, s1 = e1, s2 = e2, s3 = e3;
#pragma unroll
    for (int o = 32; o >= 1; o >>= 1) {
      s0 += __shfl_xor(s0, o, 64);
      s1 += __shfl_xor(s1, o, 64);
      s2 += __shfl_xor(s2, o, 64);
      s3 += __shfl_xor(s3, o, 64);
    }
    float i0 = 1.f / (s0 + 1e-16f), i1 = 1.f / (s1 + 1e-16f);
    float i2 = 1.f / (s2 + 1e-16f), i3 = 1.f / (s3 + 1e-16f);
    if (lane == 0) *(float4*)&den_inv[n * 4] = make_float4(i0, i1, i2, i3);
    if (lane < cnt) {
      s_al[lane * 4 + 0] = e0 * i0;
      s_al[lane * 4 + 1] = e1 * i1;
      s_al[lane * 4 + 2] = e2 * i2;
      s_al[lane * 4 + 3] = e3 * i3;
    }
    __syncthreads();
    int j = 0;
    for (; j + 8 <= cnt; j += 8) {
      unsigned oA = ((unsigned)s_src[j + 0] << 8) + loff;
      unsigned oB = ((unsigned)s_src[j + 1] << 8) + loff;
      unsigned oC = ((unsigned)s_src[j + 2] << 8) + loff;
      unsigned oD = ((unsigned)s_src[j + 3] << 8) + loff;
      unsigned oE = ((unsigned)s_src[j + 4] << 8) + loff;
      unsigned oF = ((unsigned)s_src[j + 5] << 8) + loff;
      unsigned oG = ((unsigned)s_src[j + 6] << 8) + loff;
      unsigned oH = ((unsigned)s_src[j + 7] << 8) + loff;
      unsigned rA = *(const unsigned*)&xh8[oA];
      unsigned rB = *(const unsigned*)&xh8[oB];
      unsigned rC = *(const unsigned*)&xh8[oC];
      unsigned rD = *(const unsigned*)&xh8[oD];
      unsigned rE = *(const unsigned*)&xh8[oE];
      unsigned rF = *(const unsigned*)&xh8[oF];
      unsigned rG = *(const unsigned*)&xh8[oG];
      unsigned rH = *(const unsigned*)&xh8[oH];
      float aA = s_al[(j + 0) * 4 + h], aB = s_al[(j + 1) * 4 + h];
      float aC = s_al[(j + 2) * 4 + h], aD = s_al[(j + 3) * 4 + h];
      float aE = s_al[(j + 4) * 4 + h], aF = s_al[(j + 5) * 4 + h];
      float aG = s_al[(j + 6) * 4 + h], aH = s_al[(j + 7) * 4 + h];
      f32x2 p;
      p = __builtin_amdgcn_cvt_pk_f32_fp8((int)rA, 0); acc0 += aA * p[0]; acc1 += aA * p[1];
      p = __builtin_amdgcn_cvt_pk_f32_fp8((int)rA, 1); acc2 += aA * p[0]; acc3 += aA * p[1];
      p = __builtin_amdgcn_cvt_pk_f32_fp8((int)rB, 0); acc0 += aB * p[0]; acc1 += aB * p[1];
      p = __builtin_amdgcn_cvt_pk_f32_fp8((int)rB, 1); acc2 += aB * p[0]; acc3 += aB * p[1];
      p = __builtin_amdgcn_cvt_pk_f32_fp8((int)rC, 0); acc0 += aC * p[0]; acc1 += aC * p[1];
      p = __builtin_amdgcn_cvt_pk_f32_fp8((int)rC, 1); acc2 += aC * p[0]; acc3 += aC * p[1];
      p = __builtin_amdgcn_cvt_pk_f32_fp8((int)rD, 0); acc0 += aD * p[0]; acc1 += aD * p[1];
      p = __builtin_amdgcn_cvt_pk_f32_fp8((int)rD, 1); acc2 += aD * p[0]; acc3 += aD * p[1];
      p = __builtin_amdgcn_cvt_pk_f32_fp8((int)rE, 0); acc0 += aE * p[0]; acc1 += aE * p[1];
      p = __builtin_amdgcn_cvt_pk_f32_fp8((int)rE, 1); acc2 += aE * p[0]; acc3 += aE * p[1];
      p = __builtin_amdgcn_cvt_pk_f32_fp8((int)rF, 0); acc0 += aF * p[0]; acc1 += aF * p[1];
      p = __builtin_amdgcn_cvt_pk_f32_fp8((int)rF, 1); acc2 += aF * p[0]; acc3 += aF * p[1];
      p = __builtin_amdgcn_cvt_pk_f32_fp8((int)rG, 0); acc0 += aG * p[0]; acc1 += aG * p[1];
      p = __builtin_amdgcn_cvt_pk_f32_fp8((int)rG, 1); acc2 += aG * p[0]; acc3 += aG * p[1];
      p = __builtin_amdgcn_cvt_pk_f32_fp8((int)rH, 0); acc0 += aH * p[0]; acc1 += aH * p[1];
      p = __builtin_amdgcn_cvt_pk_f32_fp8((int)rH, 1); acc2 += aH * p[0]; acc3 += aH * p[1];
    }
    for (; j + 4 <= cnt; j += 4) {
      unsigned oA = ((unsigned)s_src[j] << 8) + loff;
      unsigned oB = ((unsigned)s_src[j + 1] << 8) + loff;
      unsigned oC = ((unsigned)s_src[j + 2] << 8) + loff;
      unsigned oD = ((unsigned)s_src[j + 3] << 8) + loff;
      unsigned rA = *(const unsigned*)&xh8[oA];
      unsigned rB = *(const unsigned*)&xh8[oB];
      unsigned rC = *(const unsigned*)&xh8[oC];
      unsigned rD = *(const unsigned*)&xh8[oD];
      float aA = s_al[j * 4 + h], aB = s_al[(j + 1) * 4 + h];
      float aC = s_al[(j + 2) * 4 + h], aD = s_al[(j + 3) * 4 + h];
      f32x2 p;
      p = __builtin_amdgcn_cvt_pk_f32_fp8((int)rA, 0); acc0 += aA * p[0]; acc1 += aA * p[1];
      p = __builtin_amdgcn_cvt_pk_f32_fp8((int)rA, 1); acc2 += aA * p[0]; acc3 += aA * p[1];
      p = __builtin_amdgcn_cvt_pk_f32_fp8((int)rB, 0); acc0 += aB * p[0]; acc1 += aB * p[1];
      p = __builtin_amdgcn_cvt_pk_f32_fp8((int)rB, 1); acc2 += aB * p[0]; acc3 += aB * p[1];
      p = __builtin_amdgcn_cvt_pk_f32_fp8((int)rC, 0); acc0 += aC * p[0]; acc1 += aC * p[1];
      p = __builtin_amdgcn_cvt_pk_f32_fp8((int)rC, 1); acc2 += aC * p[0]; acc3 += aC * p[1];
      p = __builtin_amdgcn_cvt_pk_f32_fp8((int)rD, 0); acc0 += aD * p[0]; acc1 += aD * p[1];
      p = __builtin_amdgcn_cvt_pk_f32_fp8((int)rD, 1); acc2 += aD * p[0]; acc3 += aD * p[1];
    }
    for (; j < cnt; j++) {
      unsigned oA = ((unsigned)s_src[j] << 8) + loff;
      unsigned rA = *(const unsigned*)&xh8[oA];
      float aA = s_al[j * 4 + h];
      f32x2 p;
      p = __builtin_amdgcn_cvt_pk_f32_fp8((int)rA, 0); acc0 += aA * p[0]; acc1 += aA * p[1];
      p = __builtin_amdgcn_cvt_pk_f32_fp8((int)rA, 1); acc2 += aA * p[0]; acc3 += aA * p[1];
    }
  } else {
    float s0 = 0.f, s1 = 0.f, s2 = 0.f, s3 = 0.f;
    for (int j = lane; j < cnt; j += 64) {
      int src = (j < dg) ? src_list[off + j] : n;
      float4 as = *(const float4*)&a_src_n[src * 4];
      s0 += __expf(lrelu(as.x + ad.x));
      s1 += __expf(lrelu(as.y + ad.y));
      s2 += __expf(lrelu(as.z + ad.z));
      s3 += __expf(lrelu(as.w + ad.w));
    }
#pragma unroll
    for (int o = 32; o >= 1; o >>= 1) {
      s0 += __shfl_xor(s0, o, 64);
      s1 += __shfl_xor(s1, o, 64);
      s2 += __shfl_xor(s2, o, 64);
      s3 += __shfl_xor(s3, o, 64);
    }
    float i0 = 1.f / (s0 + 1e-16f), i1 = 1.f / (s1 + 1e-16f);
    float i2 = 1.f / (s2 + 1e-16f), i3 = 1.f / (s3 + 1e-16f);
    if (lane == 0) *(float4*)&den_inv[n * 4] = make_float4(i0, i1, i2, i3);
    for (int cb = 0; cb < cnt; cb += CHUNK) {
      int clen = min(CHUNK, cnt - cb);
      for (int j = lane; j < clen; j += 64) {
        int jj = cb + j;
        int src = (jj < dg) ? src_list[off + jj] : n;
        float4 as = *(const float4*)&a_src_n[src * 4];
        s_src[j] = src;
        s_al[j * 4 + 0] = __expf(lrelu(as.x + ad.x)) * i0;
        s_al[j * 4 + 1] = __expf(lrelu(as.y + ad.y)) * i1;
        s_al[j * 4 + 2] = __expf(lrelu(as.z + ad.z)) * i2;
        s_al[j * 4 + 3] = __expf(lrelu(as.w + ad.w)) * i3;
      }
      __syncthreads();
      for (int j = 0; j < clen; j++) {
        unsigned oA = ((unsigned)s_src[j] << 8) + loff;
        unsigned rA = *(const unsigned*)&xh8[oA];
        float aA = s_al[j * 4 + h];
        f32x2 p;
        p = __builtin_amdgcn_cvt_pk_f32_fp8((int)rA, 0); acc0 += aA * p[0]; acc1 += aA * p[1];
        p = __builtin_amdgcn_cvt_pk_f32_fp8((int)rA, 1); acc2 += aA * p[0]; acc3 += aA * p[1];
      }
      __syncthreads();
    }
  }

  int cb0 = (lane & 3) * 64 + (lane >> 2);
  s_tr[cb0 +  0] = __float2half(acc0 + gat_bias[cb0 +  0]);
  s_tr[cb0 + 16] = __float2half(acc1 + gat_bias[cb0 + 16]);
  s_tr[cb0 + 32] = __float2half(acc2 + gat_bias[cb0 + 32]);
  s_tr[cb0 + 48] = __float2half(acc3 + gat_bias[cb0 + 48]);
  __syncthreads();
  uint2 u = *(const uint2*)&s_tr[4 * lane];
  *(uint2*)&x2h[(size_t)n * 256 + 4 * lane] = u;
}

// ---------------- K4: per-graph tail (coalesced stage) + batched alpha -------
// Pass 1 split: (1a) 16 B/lane coalesced HBM->LDS staging (the 26 MB x2h
// stream was running at 740 GB/s with 2 B/lane strided reads — the measured
// bottleneck); (1b) stats from LDS, identical summation order.
__global__ __launch_bounds__(256) void k_tail(const int* __restrict__ gcnt,
                                              const int* __restrict__ goff,
                                              const float* __restrict__ gn_w,
                                              const float* __restrict__ gn_b,
                                              const float* __restrict__ gn_ms,
                                              const __half* __restrict__ x2h,
                                              const _Float16* __restrict__ a1w,
                                              const float* __restrict__ att1_b,
                                              const float* __restrict__ att2_w,
                                              const float* __restrict__ att2_b,
                                              const float* __restrict__ fc1_w,
                                              const float* __restrict__ fc1_b,
                                              const float* __restrict__ out_w,
                                              const float* __restrict__ out_b,
                                              const int* __restrict__ ei,
                                              const float* __restrict__ a_src_n,
                                              const float* __restrict__ a_dst_n,
                                              const float* __restrict__ den_inv,
                                              float* __restrict__ alpha_out,
                                              float* __restrict__ outp) {
  __shared__ __align__(16) __half s_x[GLDS * SXP];   // ~147.8 KB, bank-padded
  __shared__ __align__(16) float s_sc[256];
  __shared__ __align__(16) float s_sh[256];
  __shared__ float s_gate[GMAX];          // exp(sigmoid(gate)) per local node
  __shared__ __align__(16) float pool_s[256];
  __shared__ float hred[128];
  __shared__ float red[4];
  int g = blockIdx.x, tid = threadIdx.x, lane = tid & 63, wid = tid >> 6;
  int cnt = gcnt[g], start = goff[g];
  int am = lane & 15, quad = lane >> 4;

  if (cnt <= GLDS) {
    // ---- pass 1a: coalesced stage HBM -> LDS (16 B/lane, 4-deep) ----
    {
      int cg = tid & 31, r8 = tid >> 5;
      const __half* p = x2h + (size_t)start * 256 + cg * 8;
      int i = r8;
      for (; i + 24 < cnt; i += 32) {
        uint4 v0 = *(const uint4*)&p[(size_t)(i +  0) * 256];
        uint4 v1 = *(const uint4*)&p[(size_t)(i +  8) * 256];
        uint4 v2 = *(const uint4*)&p[(size_t)(i + 16) * 256];
        uint4 v3 = *(const uint4*)&p[(size_t)(i + 24) * 256];
        *(uint4*)&s_x[(i +  0) * SXP + cg * 8] = v0;
        *(uint4*)&s_x[(i +  8) * SXP + cg * 8] = v1;
        *(uint4*)&s_x[(i + 16) * SXP + cg * 8] = v2;
        *(uint4*)&s_x[(i + 24) * SXP + cg * 8] = v3;
      }
      for (; i < cnt; i += 8) {
        uint4 v = *(const uint4*)&p[(size_t)i * 256];
        *(uint4*)&s_x[i * SXP + cg * 8] = v;
      }
    }
    __syncthreads();

    // ---- pass 1b: stats from LDS (thread = channel; same sum order) ----
    {
      int c = tid;
      float S = 0.f, S2 = 0.f;
      int i = 0;
      for (; i + 7 < cnt; i += 8) {
        float v0 = __half2float(s_x[(i + 0) * SXP + c]);
        float v1 = __half2float(s_x[(i + 1) * SXP + c]);
        float v2 = __half2float(s_x[(i + 2) * SXP + c]);
        float v3 = __half2float(s_x[(i + 3) * SXP + c]);
        float v4 = __half2float(s_x[(i + 4) * SXP + c]);
        float v5 = __half2float(s_x[(i + 5) * SXP + c]);
        float v6 = __half2float(s_x[(i + 6) * SXP + c]);
        float v7 = __half2float(s_x[(i + 7) * SXP + c]);
        S  += ((v0 + v1) + (v2 + v3)) + ((v4 + v5) + (v6 + v7));
        S2 += ((v0 * v0 + v1 * v1) + (v2 * v2 + v3 * v3)) +
              ((v4 * v4 + v5 * v5) + (v6 * v6 + v7 * v7));
      }
      for (; i < cnt; i++) {
        float v = __half2float(s_x[i * SXP + c]);
        S += v; S2 += v * v;
      }
      float fc = fmaxf((float)cnt, 1.f);
      float mean = S / fc;
      float mm = mean * gn_ms[c];
      float var = fmaxf(S2 / fc - 2.f * mm * mean + mm * mm, 0.f);
      float sc = gn_w[c] / sqrtf(var + GEPS);
      s_sc[c] = sc;
      s_sh[c] = gn_b[c] - sc * mm;
    }
    __syncthreads();

    // ---- gate MLP from LDS: 16 nodes / wave via MFMA ----
    float b1 = att1_b[am], w2 = att2_w[am], b2 = att2_b[0];
    const _Float16* bp = a1w + am * 256 + quad * 8;
    for (int i0 = wid * 16; i0 < cnt; i0 += 64) {
      int li = i0 + am;
      if (li > cnt - 1) li = cnt - 1;          // clamp (masked below)
      const __half* xp = &s_x[li * SXP + quad * 8];
      f32x4 ga = (f32x4){0.f, 0.f, 0.f, 0.f};
#pragma unroll
      for (int kb = 0; kb < 8; kb++) {
        f16x8 xv = *(const f16x8*)(xp + kb * 32);
        int cb = quad * 8 + kb * 32;
        float4 sc0 = *(const float4*)&s_sc[cb];
        float4 sc1 = *(const float4*)&s_sc[cb + 4];
        float4 sh0 = *(const float4*)&s_sh[cb];
        float4 sh1 = *(const float4*)&s_sh[cb + 4];
        f16x8 a;
        a[0] = (_Float16)fmaxf(sc0.x * (float)xv[0] + sh0.x, 0.f);
        a[1] = (_Float16)fmaxf(sc0.y * (float)xv[1] + sh0.y, 0.f);
        a[2] = (_Float16)fmaxf(sc0.z * (float)xv[2] + sh0.z, 0.f);
        a[3] = (_Float16)fmaxf(sc0.w * (float)xv[3] + sh0.w, 0.f);
        a[4] = (_Float16)fmaxf(sc1.x * (float)xv[4] + sh1.x, 0.f);
        a[5] = (_Float16)fmaxf(sc1.y * (float)xv[5] + sh1.y, 0.f);
        a[6] = (_Float16)fmaxf(sc1.z * (float)xv[6] + sh1.z, 0.f);
        a[7] = (_Float16)fmaxf(sc1.w * (float)xv[7] + sh1.w, 0.f);
        f16x8 b = *(const f16x8*)(bp + kb * 32);
        ga = __builtin_amdgcn_mfma_f32_16x16x32_f16(a, b, ga, 0, 0, 0);
      }
#pragma unroll
      for (int r = 0; r < 4; r++) {
        float t = w2 * fmaxf(ga[r] + b1, 0.f);
#pragma unroll
        for (int o = 1; o < 16; o <<= 1) t += __shfl_xor(t, o, 64);
        if (am == 0) {
          int li2 = i0 + quad * 4 + r;
          if (li2 < cnt) s_gate[li2] = __expf(1.f / (1.f + __expf(-(t + b2))));
        }
      }
    }
    __syncthreads();

    // ---- gate softmax denominator ----
    float ls = 0.f;
    for (int i = tid; i < cnt; i += 256) ls += s_gate[i];
#pragma unroll
    for (int o = 32; o >= 1; o >>= 1) ls += __shfl_xor(ls, o, 64);
    if (lane == 0) red[wid] = ls;
    __syncthreads();
    float rden = 1.f / (red[0] + red[1] + red[2] + red[3] + 1e-16f);

    // ---- weighted pool from LDS (thread = channel) ----
    {
      int c = tid;
      float sc = s_sc[c], sh = s_sh[c];
      float a0 = 0.f, a1_ = 0.f, a2 = 0.f, a3 = 0.f;
      float a4 = 0.f, a5 = 0.f, a6 = 0.f, a7 = 0.f;
      int i = 0;
      for (; i + 7 < cnt; i += 8) {
        float v0 = __half2float(s_x[(i + 0) * SXP + c]);
        float v1 = __half2float(s_x[(i + 1) * SXP + c]);
        float v2 = __half2float(s_x[(i + 2) * SXP + c]);
        float v3 = __half2float(s_x[(i + 3) * SXP + c]);
        float v4 = __half2float(s_x[(i + 4) * SXP + c]);
        float v5 = __half2float(s_x[(i + 5) * SXP + c]);
        float v6 = __half2float(s_x[(i + 6) * SXP + c]);
        float v7 = __half2float(s_x[(i + 7) * SXP + c]);
        a0 += s_gate[i + 0] * fmaxf(sc * v0 + sh, 0.f);
        a1_ += s_gate[i + 1] * fmaxf(sc * v1 + sh, 0.f);
        a2 += s_gate[i + 2] * fmaxf(sc * v2 + sh, 0.f);
        a3 += s_gate[i + 3] * fmaxf(sc * v3 + sh, 0.f);
        a4 += s_gate[i + 4] * fmaxf(sc * v4 + sh, 0.f);
        a5 += s_gate[i + 5] * fmaxf(sc * v5 + sh, 0.f);
        a6 += s_gate[i + 6] * fmaxf(sc * v6 + sh, 0.f);
        a7 += s_gate[i + 7] * fmaxf(sc * v7 + sh, 0.f);
      }
      for (; i < cnt; i++)
        a0 += s_gate[i] * fmaxf(sc * __half2float(s_x[i * SXP + c]) + sh, 0.f);
      pool_s[c] = ((((a0 + a1_) + (a2 + a3)) + ((a4 + a5) + (a6 + a7)))) * rden;
    }
  } else {
    // ---- fallback: original 3-pass global path (cnt > GLDS, ~never) ----
    {
      int c = tid;
      const __half* p = x2h + (size_t)start * 256 + c;
      float S = 0.f, S2 = 0.f;
      int i = 0;
      for (; i + 7 < cnt; i += 8) {
        float v0 = __half2float(p[(size_t)(i + 0) * 256]);
        float v1 = __half2float(p[(size_t)(i + 1) * 256]);
        float v2 = __half2float(p[(size_t)(i + 2) * 256]);
        float v3 = __half2float(p[(size_t)(i + 3) * 256]);
        float v4 = __half2float(p[(size_t)(i + 4) * 256]);
        float v5 = __half2float(p[(size_t)(i + 5) * 256]);
        float v6 = __half2float(p[(size_t)(i + 6) * 256]);
        float v7 = __half2float(p[(size_t)(i + 7) * 256]);
        S  += ((v0 + v1) + (v2 + v3)) + ((v4 + v5) + (v6 + v7));
        S2 += ((v0 * v0 + v1 * v1) + (v2 * v2 + v3 * v3)) +
              ((v4 * v4 + v5 * v5) + (v6 * v6 + v7 * v7));
      }
      for (; i < cnt; i++) { float v = __half2float(p[(size_t)i * 256]); S += v; S2 += v * v; }
      float fc = fmaxf((float)cnt, 1.f);
      float mean = S / fc;
      float mm = mean * gn_ms[c];
      float var = fmaxf(S2 / fc - 2.f * mm * mean + mm * mm, 0.f);
      float sc = gn_w[c] / sqrtf(var + GEPS);
      s_sc[c] = sc;
      s_sh[c] = gn_b[c] - sc * mm;
    }
    __syncthreads();

    float b1 = att1_b[am], w2 = att2_w[am], b2 = att2_b[0];
    const _Float16* bp = a1w + am * 256 + quad * 8;
    for (int i0 = wid * 16; i0 < cnt; i0 += 64) {
      int node = start + i0 + am;
      if (node > NN - 1) node = NN - 1;
      const __half* xp = x2h + (size_t)node * 256 + quad * 8;
      f32x4 ga = (f32x4){0.f, 0.f, 0.f, 0.f};
#pragma unroll
      for (int kb = 0; kb < 8; kb++) {
        f16x8 xv = *(const f16x8*)(xp + kb * 32);
        int cb = quad * 8 + kb * 32;
        float4 sc0 = *(const float4*)&s_sc[cb];
        float4 sc1 = *(const float4*)&s_sc[cb + 4];
        float4 sh0 = *(const float4*)&s_sh[cb];
        float4 sh1 = *(const float4*)&s_sh[cb + 4];
        f16x8 a;
        a[0] = (_Float16)fmaxf(sc0.x * (float)xv[0] + sh0.x, 0.f);
        a[1] = (_Float16)fmaxf(sc0.y * (float)xv[1] + sh0.y, 0.f);
        a[2] = (_Float16)fmaxf(sc0.z * (float)xv[2] + sh0.z, 0.f);
        a[3] = (_Float16)fmaxf(sc0.w * (float)xv[3] + sh0.w, 0.f);
        a[4] = (_Float16)fmaxf(sc1.x * (float)xv[4] + sh1.x, 0.f);
        a[5] = (_Float16)fmaxf(sc1.y * (float)xv[5] + sh1.y, 0.f);
        a[6] = (_Float16)fmaxf(sc1.z * (float)xv[6] + sh1.z, 0.f);
        a[7] = (_Float16)fmaxf(sc1.w * (float)xv[7] + sh1.w, 0.f);
        f16x8 b = *(const f16x8*)(bp + kb * 32);
        ga = __builtin_amdgcn_mfma_f32_16x16x32_f16(a, b, ga, 0, 0, 0);
      }
#pragma unroll
      for (int r = 0; r < 4; r++) {
        float t = w2 * fmaxf(ga[r] + b1, 0.f);
#pragma unroll
        for (int o = 1; o < 16; o <<= 1) t += __shfl_xor(t, o, 64);
        if (am == 0) {
          int li = i0 + quad * 4 + r;
          if (li < cnt && li < GMAX)
            s_gate[li] = __expf(1.f / (1.f + __expf(-(t + b2))));
        }
      }
    }
    __syncthreads();

    float ls = 0.f;
    for (int i = tid; i < cnt; i += 256) ls += (i < GMAX) ? s_gate[i] : 0.f;
#pragma unroll
    for (int o = 32; o >= 1; o >>= 1) ls += __shfl_xor(ls, o, 64);
    if (lane == 0) red[wid] = ls;
    __syncthreads();
    float rden = 1.f / (red[0] + red[1] + red[2] + red[3] + 1e-16f);

    {
      int c = tid;
      float sc = s_sc[c], sh = s_sh[c];
      const __half* p = x2h + (size_t)start * 256 + c;
      float a0 = 0.f;
      for (int i = 0; i < cnt; i++) {
        float w = (i < GMAX) ? s_gate[i] : 0.f;
        a0 += w * fmaxf(sc * __half2float(p[(size_t)i * 256]) + sh, 0.f);
      }
      pool_s[c] = a0 * rden;
    }
  }
  __syncthreads();

  // ---- fc1 + out head (common) ----
  float4 psv = *(const float4*)&pool_s[4 * lane];
  for (int j0 = 0; j0 < 32; j0++) {
    int j = wid * 32 + j0;
    float4 w = *(const float4*)&fc1_w[j * 256 + 4 * lane];
    float d = w.x * psv.x + w.y * psv.y + w.z * psv.z + w.w * psv.w;
#pragma unroll
    for (int o = 32; o >= 1; o >>= 1) d += __shfl_xor(d, o, 64);
    if (lane == 0) hred[j] = fmaxf(d + fc1_b[j], 0.f) * out_w[j];
  }
  __syncthreads();
  if (tid < 128) {
    float v = hred[tid];
#pragma unroll
    for (int o = 32; o >= 1; o >>= 1) v += __shfl_xor(v, o, 64);
    if (lane == 0) red[wid] = v;
  }
  __syncthreads();
  if (tid == 0) outp[g] = 1.f / (1.f + __expf(-(red[0] + red[1] + out_b[0])));

  // ---- alpha edge slab: 4 edges in flight per thread (batched loads) --------
  {
    int base = g * EPT;
    int end = min(base + EPT, NE + NN);
    int idx = base + tid;
    for (; idx + 768 < end; idx += 1024) {
      int i0 = idx, i1 = idx + 256, i2 = idx + 512, i3 = idx + 768;
      int s0, d0, s1, d1, s2, d2, s3, d3;
      if (i0 < NE) { s0 = ei[i0]; d0 = ei[NE + i0]; } else { s0 = i0 - NE; d0 = s0; }
      if (i1 < NE) { s1 = ei[i1]; d1 = ei[NE + i1]; } else { s1 = i1 - NE; d1 = s1; }
      if (i2 < NE) { s2 = ei[i2]; d2 = ei[NE + i2]; } else { s2 = i2 - NE; d2 = s2; }
      if (i3 < NE) { s3 = ei[i3]; d3 = ei[NE + i3]; } else { s3 = i3 - NE; d3 = s3; }
      float4 as0 = *(const float4*)&a_src_n[s0 * 4];
      float4 ad0 = *(const float4*)&a_dst_n[d0 * 4];
      float4 iv0 = *(const float4*)&den_inv[d0 * 4];
      float4 as1 = *(const float4*)&a_src_n[s1 * 4];
      float4 ad1 = *(const float4*)&a_dst_n[d1 * 4];
      float4 iv1 = *(const float4*)&den_inv[d1 * 4];
      float4 as2 = *(const float4*)&a_src_n[s2 * 4];
      float4 ad2 = *(const float4*)&a_dst_n[d2 * 4];
      float4 iv2 = *(const float4*)&den_inv[d2 * 4];
      float4 as3 = *(const float4*)&a_src_n[s3 * 4];
      float4 ad3 = *(const float4*)&a_dst_n[d3 * 4];
      float4 iv3 = *(const float4*)&den_inv[d3 * 4];
      float4 a;
      a.x = __expf(lrelu(as0.x + ad0.x)) * iv0.x;
      a.y = __expf(lrelu(as0.y + ad0.y)) * iv0.y;
      a.z = __expf(lrelu(as0.z + ad0.z)) * iv0.z;
      a.w = __expf(lrelu(as0.w + ad0.w)) * iv0.w;
      *(float4*)&alpha_out[(size_t)i0 * 4] = a;
      a.x = __expf(lrelu(as1.x + ad1.x)) * iv1.x;
      a.y = __expf(lrelu(as1.y + ad1.y)) * iv1.y;
      a.z = __expf(lrelu(as1.z + ad1.z)) * iv1.z;
      a.w = __expf(lrelu(as1.w + ad1.w)) * iv1.w;
      *(float4*)&alpha_out[(size_t)i1 * 4] = a;
      a.x = __expf(lrelu(as2.x + ad2.x)) * iv2.x;
      a.y = __expf(lrelu(as2.y + ad2.y)) * iv2.y;
      a.z = __expf(lrelu(as2.z + ad2.z)) * iv2.z;
      a.w = __expf(lrelu(as2.w + ad2.w)) * iv2.w;
      *(float4*)&alpha_out[(size_t)i2 * 4] = a;
      a.x = __expf(lrelu(as3.x + ad3.x)) * iv3.x;
      a.y = __expf(lrelu(as3.y + ad3.y)) * iv3.y;
      a.z = __expf(lrelu(as3.z + ad3.z)) * iv3.z;
      a.w = __expf(lrelu(as3.w + ad3.w)) * iv3.w;
      *(float4*)&alpha_out[(size_t)i3 * 4] = a;
    }
    for (; idx < end; idx += 256) {
      int s, d;
      if (idx < NE) { s = ei[idx]; d = ei[NE + idx]; }
      else          { s = idx - NE; d = s; }
      float4 as = *(const float4*)&a_src_n[s * 4];
      float4 ad = *(const float4*)&a_dst_n[d * 4];
      float4 iv = *(const float4*)&den_inv[d * 4];
      float4 a;
      a.x = __expf(lrelu(as.x + ad.x)) * iv.x;
      a.y = __expf(lrelu(as.y + ad.y)) * iv.y;
      a.z = __expf(lrelu(as.z + ad.z)) * iv.z;
      a.w = __expf(lrelu(as.w + ad.w)) * iv.w;
      *(float4*)&alpha_out[(size_t)idx * 4] = a;
    }
  }
}

// -----------------------------------------------------------------------------
extern "C" void kernel_launch(void* const* d_in, const int* in_sizes, int n_in,
                              void* d_out, int out_size, void* d_ws, size_t ws_size,
                              hipStream_t stream) {
  const float* x        = (const float*)d_in[0];
  const int*   ei       = (const int*)d_in[1];
  const int*   batch    = (const int*)d_in[2];
  const float* lin_w    = (const float*)d_in[3];
  const float* att_src  = (const float*)d_in[4];
  const float* att_dst  = (const float*)d_in[5];
  const float* gat_bias = (const float*)d_in[6];
  const float* gn_w     = (const float*)d_in[7];
  const float* gn_b     = (const float*)d_in[8];
  const float* gn_ms    = (const float*)d_in[9];
  const float* fc1_w    = (const float*)d_in[10];
  const float* fc1_b    = (const float*)d_in[11];
  const float* out_w    = (const float*)d_in[12];
  const float* out_b    = (const float*)d_in[13];
  const float* att1_w   = (const float*)d_in[14];
  const float* att1_b   = (const float*)d_in[15];
  const float* att2_w   = (const float*)d_in[16];
  const float* att2_b   = (const float*)d_in[17];

  float* outp  = (float*)d_out;       // [256]
  float* alpha = outp + NG;           // [(E+N)*4]

  char* wsb = (char*)d_ws;
  size_t o = 0;
  auto A = [&](size_t bytes) -> char* {
    char* p = wsb + o;
    o += (bytes + 255) & ~(size_t)255;
    return p;
  };
  unsigned char* xh8 = (unsigned char*)A((size_t)NN * 256);
  __half*   x2h      = (__half*)A((size_t)NN * 256 * 2);
  _Float16* wh       = (_Float16*)A((size_t)256 * 64 * 2);
  _Float16* a1w      = (_Float16*)A((size_t)16 * 256 * 2);
  _Float16* watt     = (_Float16*)A((size_t)16 * 64 * 2);
  float* a_src_n  = (float*)A((size_t)NN * 4 * 4);
  float* a_dst_n  = (float*)A((size_t)NN * 4 * 4);
  float* den_inv  = (float*)A((size_t)NN * 4 * 4);
  int*   deg      = (int*)A((size_t)NN * 4);
  int*   gcnt     = (int*)A((size_t)NG * 4);
  int*   offs     = (int*)A((size_t)NN * 4);
  int*   goff     = (int*)A((size_t)NG * 4);
  int*   src_list = (int*)A((size_t)NE * 4);
  int2*  ebuf     = (int2*)A((size_t)NB * CAP * 8);
  int*   bucket_cnt  = (int*)A((size_t)NB * 4);

  k_misc<<<22, 256, 0, stream>>>(lin_w, wh, att1_w, a1w, att_src, att_dst, watt,
                                 batch, goff, gcnt, bucket_cnt);
  k_linbin<<<NLINB + NAB, 256, 0, stream>>>(x, wh, watt, xh8, a_src_n, a_dst_n,
                                            ei, bucket_cnt, ebuf);
  k_binB<<<NB, 256, 0, stream>>>(ebuf, bucket_cnt, deg, offs, src_list);
  k_gat<<<NN, 64, 0, stream>>>(xh8, a_src_n, a_dst_n, offs, deg, src_list,
                               gat_bias, x2h, den_inv);
  k_tail<<<NG, 256, 0, stream>>>(gcnt, goff, gn_w, gn_b, gn_ms, x2h,
                                 a1w, att1_b, att2_w, att2_b, fc1_w, fc1_b,
                                 out_w, out_b, ei, a_src_n, a_dst_n, den_inv,
                                 alpha, outp);
}

// Round 15
// 213.121 us; speedup vs baseline: 1.0565x; 1.0345x over previous
//
#include <hip/hip_runtime.h>
#include <hip/hip_fp16.h>
#include <math.h>

#define NN 50000
#define NE 800000
#define NG 256
#define NEG_SLOPE 0.2f
#define GEPS 1e-5f
#define CHUNK 64
#define NB 196          // coarse buckets of 256 node-ids (dst >> 8)
#define CAP 6144        // per-bucket segment capacity (mean 4081)
#define NAB 261         // binA blocks = ceil(NE/EPB)
#define EPB 3072        // edges per binA block (12/thread, int4-aligned)
#define NLINB 782       // (NN+63)/64 lin blocks
#define EPT 3321        // alpha edges per tail block = ceil((NE+NN)/NG)
#define GMAX 512        // fallback gate capacity
#define GLDS 280        // staged rows per graph (actual max ~240)
#define SXP 264         // padded s_x row stride in halves (528 B -> bank-safe)

typedef _Float16 f16x8 __attribute__((ext_vector_type(8)));
typedef _Float16 f16x4 __attribute__((ext_vector_type(4)));
typedef float f32x4 __attribute__((ext_vector_type(4)));
typedef float f32x2 __attribute__((ext_vector_type(2)));

__device__ __forceinline__ float lrelu(float v){ return v > 0.f ? v : NEG_SLOPE * v; }

// ---------------- K0: weight converts + goff + bucket zero + w_att build -----
__global__ __launch_bounds__(256) void k_misc(const float* __restrict__ lin_w,
                                              _Float16* __restrict__ wh,
                                              const float* __restrict__ att1_w,
                                              _Float16* __restrict__ a1w,
                                              const float* __restrict__ att_src,
                                              const float* __restrict__ att_dst,
                                              _Float16* __restrict__ watt,
                                              const int* __restrict__ batch,
                                              int* __restrict__ goff,
                                              int* __restrict__ gcnt,
                                              int* __restrict__ bucket_cnt) {
  int b = blockIdx.x, tid = threadIdx.x;
  if (b == 0) {
    if (tid < NB) bucket_cnt[tid] = 0;
    int g = tid;
    int lo = 0, hi = NN;
    while (lo < hi) { int mid = (lo + hi) >> 1; if (batch[mid] < g) lo = mid + 1; else hi = mid; }
    int start = lo;
    lo = 0; hi = NN;
    while (lo < hi) { int mid = (lo + hi) >> 1; if (batch[mid] < g + 1) lo = mid + 1; else hi = mid; }
    goff[g] = start;
    gcnt[g] = lo - start;
  } else if (b <= 16) {
    int i0 = (b - 1) * 1024 + tid * 4;
    float4 f = *(const float4*)&lin_w[i0];
    f16x4 h4;
    h4[0] = (_Float16)f.x; h4[1] = (_Float16)f.y; h4[2] = (_Float16)f.z; h4[3] = (_Float16)f.w;
    *(f16x4*)&wh[i0] = h4;
  } else if (b <= 20) {
    int i0 = (b - 17) * 1024 + tid * 4;
    float4 f = *(const float4*)&att1_w[i0];
    f16x4 h4;
    h4[0] = (_Float16)f.x; h4[1] = (_Float16)f.y; h4[2] = (_Float16)f.z; h4[3] = (_Float16)f.w;
    *(f16x4*)&a1w[i0] = h4;
  } else {
    for (int e = tid; e < 16 * 64; e += 256) {
      int row = e >> 6, k = e & 63;
      float s = 0.f;
      if (row < 8) {
        int h = row & 3;
        const float* av = (row < 4) ? att_src : att_dst;
        for (int c = 0; c < 64; c++)
          s += av[h * 64 + c] * lin_w[(h * 64 + c) * 64 + k];
      }
      watt[e] = (_Float16)s;
    }
  }
}

// ---------------- K1 fused: MFMA lin (blocks < NLINB) | binA sort (rest) ------
__device__ __forceinline__ void lin_body(char* smem,
                                         const float* __restrict__ x,
                                         const _Float16* __restrict__ wh,
                                         const _Float16* __restrict__ watt,
                                         unsigned char* __restrict__ xh8,
                                         float* __restrict__ a_src_n,
                                         float* __restrict__ a_dst_n) {
  unsigned char* s_f8 = (unsigned char*)smem;     // 16 KB (4 waves x 4 KB)
  int w = threadIdx.x >> 6, lane = threadIdx.x & 63;
  int nb = blockIdx.x * 64 + w * 16;
  if (nb >= NN) return;                 // per-wave LDS region; no barriers used
  int am = lane & 15, quad = lane >> 4;
  int wb = w * 4096;

  const float* xr = x + (size_t)(nb + am) * 64 + quad * 8;
  float4 f0 = *(const float4*)(xr);
  float4 f1 = *(const float4*)(xr + 4);
  float4 f2 = *(const float4*)(xr + 32);
  float4 f3 = *(const float4*)(xr + 36);
  f16x8 a0, a1;
  a0[0] = (_Float16)f0.x; a0[1] = (_Float16)f0.y; a0[2] = (_Float16)f0.z; a0[3] = (_Float16)f0.w;
  a0[4] = (_Float16)f1.x; a0[5] = (_Float16)f1.y; a0[6] = (_Float16)f1.z; a0[7] = (_Float16)f1.w;
  a1[0] = (_Float16)f2.x; a1[1] = (_Float16)f2.y; a1[2] = (_Float16)f2.z; a1[3] = (_Float16)f2.w;
  a1[4] = (_Float16)f3.x; a1[5] = (_Float16)f3.y; a1[6] = (_Float16)f3.z; a1[7] = (_Float16)f3.w;

  f32x4 acc[16];
#pragma unroll
  for (int ct = 0; ct < 16; ct++) acc[ct] = (f32x4){0.f, 0.f, 0.f, 0.f};

#pragma unroll
  for (int ct = 0; ct < 16; ct++) {
    const _Float16* wbp = wh + (size_t)(ct * 16 + am) * 64 + quad * 8;
    f16x8 b0 = *(const f16x8*)(wbp);
    f16x8 b1 = *(const f16x8*)(wbp + 32);
    acc[ct] = __builtin_amdgcn_mfma_f32_16x16x32_f16(a0, b0, acc[ct], 0, 0, 0);
    acc[ct] = __builtin_amdgcn_mfma_f32_16x16x32_f16(a1, b1, acc[ct], 0, 0, 0);
  }

  // attention projections via one extra MFMA pair (replaces 128-shfl reduce)
  {
    const _Float16* wap = watt + am * 64 + quad * 8;
    f16x8 t0 = *(const f16x8*)(wap);
    f16x8 t1 = *(const f16x8*)(wap + 32);
    f32x4 acca = (f32x4){0.f, 0.f, 0.f, 0.f};
    acca = __builtin_amdgcn_mfma_f32_16x16x32_f16(a0, t0, acca, 0, 0, 0);
    acca = __builtin_amdgcn_mfma_f32_16x16x32_f16(a1, t1, acca, 0, 0, 0);
    if (am < 8) {
#pragma unroll
      for (int r = 0; r < 4; r++) {
        int node = nb + quad * 4 + r;
        if (am < 4) a_src_n[node * 4 + am] = acca[r];
        else        a_dst_n[node * 4 + (am - 4)] = acca[r];
      }
    }
  }

#pragma unroll
  for (int r = 0; r < 4; r++) {
    uint4 u;
    int t;
    t = __builtin_amdgcn_cvt_pk_fp8_f32(acc[0][r],  acc[1][r],  0, 0);
    t = __builtin_amdgcn_cvt_pk_fp8_f32(acc[2][r],  acc[3][r],  t, 1);
    u.x = (unsigned)t;
    t = __builtin_amdgcn_cvt_pk_fp8_f32(acc[4][r],  acc[5][r],  0, 0);
    t = __builtin_amdgcn_cvt_pk_fp8_f32(acc[6][r],  acc[7][r],  t, 1);
    u.y = (unsigned)t;
    t = __builtin_amdgcn_cvt_pk_fp8_f32(acc[8][r],  acc[9][r],  0, 0);
    t = __builtin_amdgcn_cvt_pk_fp8_f32(acc[10][r], acc[11][r], t, 1);
    u.z = (unsigned)t;
    t = __builtin_amdgcn_cvt_pk_fp8_f32(acc[12][r], acc[13][r], 0, 0);
    t = __builtin_amdgcn_cvt_pk_fp8_f32(acc[14][r], acc[15][r], t, 1);
    u.w = (unsigned)t;
    *(uint4*)&s_f8[wb + (quad * 4 + r) * 256 + am * 16] = u;
  }
#pragma unroll
  for (int p = 0; p < 4; p++) {
    uint4 u = *(const uint4*)&s_f8[wb + p * 1024 + lane * 16];
    *(uint4*)&xh8[(size_t)nb * 256 + p * 1024 + lane * 16] = u;
  }
}

// binA: 3072 edges/block, 12 edges/thread in registers (3x int4 coalesced
// loads for dst, 3x int4 for src); dst kept in regs across both passes.
__device__ __forceinline__ void binA_body(char* smem, int b,
                                          const int* __restrict__ ei,
                                          int* __restrict__ bucket_cnt,
                                          int2* __restrict__ ebuf) {
  int2* sorted = (int2*)smem;                         // 24576 B
  int*  hist   = (int*)(smem + 24576);                // 784 B
  int*  lbase  = (int*)(smem + 25360);                // 784 B
  int*  cur    = (int*)(smem + 26144);                // 784 B
  int*  runb   = (int*)(smem + 26928);                // 784 B
  int*  wsum   = (int*)(smem + 27712);                // 16 B
  int tid = threadIdx.x, lane = tid & 63, wid = tid >> 6;
  int e0 = b * EPB, e1 = min(e0 + EPB, NE);
  int n = e1 - e0;
  bool full = (e0 + EPB <= NE);

  int dd[12];
  if (full) {
#pragma unroll
    for (int r = 0; r < 3; r++) {
      int e = e0 + r * 1024 + tid * 4;
      int4 v = *(const int4*)&ei[NE + e];
      dd[r * 4 + 0] = v.x; dd[r * 4 + 1] = v.y;
      dd[r * 4 + 2] = v.z; dd[r * 4 + 3] = v.w;
    }
  } else {
#pragma unroll
    for (int r = 0; r < 3; r++)
#pragma unroll
      for (int k = 0; k < 4; k++) {
        int e = e0 + r * 1024 + tid * 4 + k;
        dd[r * 4 + k] = (e < e1) ? ei[NE + e] : -1;   // -1 = invalid sentinel
      }
  }
  if (tid < NB) hist[tid] = 0;
  __syncthreads();
#pragma unroll
  for (int q = 0; q < 12; q++)
    if (dd[q] >= 0) atomicAdd(&hist[dd[q] >> 8], 1);
  __syncthreads();
  {
    int v = (tid < NB) ? hist[tid] : 0;
    int s = v;
#pragma unroll
    for (int o = 1; o < 64; o <<= 1) { int t = __shfl_up(s, o, 64); if (lane >= o) s += t; }
    if (lane == 63) wsum[wid] = s;
    __syncthreads();
    int wbase = 0;
    for (int k = 0; k < wid; k++) wbase += wsum[k];
    if (tid < NB) {
      int ex = wbase + s - v;
      lbase[tid] = ex;
      cur[tid] = ex;
      runb[tid] = atomicAdd(&bucket_cnt[tid], v);
    }
  }
  __syncthreads();
  int ss[12];
  if (full) {
#pragma unroll
    for (int r = 0; r < 3; r++) {
      int e = e0 + r * 1024 + tid * 4;
      int4 v = *(const int4*)&ei[e];
      ss[r * 4 + 0] = v.x; ss[r * 4 + 1] = v.y;
      ss[r * 4 + 2] = v.z; ss[r * 4 + 3] = v.w;
    }
  } else {
#pragma unroll
    for (int r = 0; r < 3; r++)
#pragma unroll
      for (int k = 0; k < 4; k++) {
        int e = e0 + r * 1024 + tid * 4 + k;
        ss[r * 4 + k] = (e < e1) ? ei[e] : 0;
      }
  }
#pragma unroll
  for (int q = 0; q < 12; q++) {
    int d = dd[q];
    if (d >= 0) {
      int lp = atomicAdd(&cur[d >> 8], 1);
      sorted[lp] = make_int2(d, ss[q]);
    }
  }
  __syncthreads();
  for (int i = tid; i < n; i += 256) {
    int2 e = sorted[i];
    int bk = e.x >> 8;
    int slot = runb[bk] + (i - lbase[bk]);
    if (slot < CAP) ebuf[(size_t)bk * CAP + slot] = e;
  }
}

__global__ __launch_bounds__(256) void k_linbin(const float* __restrict__ x,
                                                const _Float16* __restrict__ wh,
                                                const _Float16* __restrict__ watt,
                                                unsigned char* __restrict__ xh8,
                                                float* __restrict__ a_src_n,
                                                float* __restrict__ a_dst_n,
                                                const int* __restrict__ ei,
                                                int* __restrict__ bucket_cnt,
                                                int2* __restrict__ ebuf) {
  __shared__ __align__(16) char smem[27744];
  if (blockIdx.x < NLINB)
    lin_body(smem, x, wh, watt, xh8, a_src_n, a_dst_n);
  else
    binA_body(smem, blockIdx.x - NLINB, ei, bucket_cnt, ebuf);
}

// ---------------- K2: per-bucket local hist+scan+scatter (inline bscan) -------
__global__ __launch_bounds__(256) void k_binB(const int2* __restrict__ ebuf,
                                              const int* __restrict__ bucket_cnt,
                                              int* __restrict__ deg,
                                              int* __restrict__ offs,
                                              int* __restrict__ src_list) {
  __shared__ int hist[256];
  __shared__ int cur[256];
  __shared__ int wsum[4];
  __shared__ int bbase[NB];
  int b = blockIdx.x, tid = threadIdx.x, lane = tid & 63, wid = tid >> 6;
  // inline scan of all bucket counts -> bbase
  {
    int v = (tid < NB) ? min(bucket_cnt[tid], CAP) : 0;
    int s = v;
#pragma unroll
    for (int o = 1; o < 64; o <<= 1) { int t = __shfl_up(s, o, 64); if (lane >= o) s += t; }
    if (lane == 63) wsum[wid] = s;
    __syncthreads();
    int wbase = 0;
    for (int k = 0; k < wid; k++) wbase += wsum[k];
    if (tid < NB) bbase[tid] = wbase + s - v;
  }
  __syncthreads();
  int cnt = min(bucket_cnt[b], CAP);
  int base = bbase[b];
  const int2* seg = ebuf + (size_t)b * CAP;
  hist[tid] = 0;
  __syncthreads();
  for (int i = tid; i < cnt; i += 256) atomicAdd(&hist[seg[i].x & 255], 1);
  __syncthreads();
  int v = hist[tid];
  int s = v;
#pragma unroll
  for (int o = 1; o < 64; o <<= 1) { int t = __shfl_up(s, o, 64); if (lane >= o) s += t; }
  if (lane == 63) wsum[wid] = s;
  __syncthreads();
  int wbase = 0;
  for (int k = 0; k < wid; k++) wbase += wsum[k];
  int excl = wbase + s - v;
  int node = b * 256 + tid;
  if (node < NN) {
    deg[node] = v;
    offs[node] = base + excl;
  }
  cur[tid] = excl;
  __syncthreads();
  for (int i = tid; i < cnt; i += 256) {
    int2 e = seg[i];
    int pos = base + atomicAdd(&cur[e.x & 255], 1);
    src_list[pos] = e.y;
  }
}

// ---------------- K3: GAT softmax + fp8 aggregation (dword gather, 8-deep) ----
__global__ __launch_bounds__(64) void k_gat(const unsigned char* __restrict__ xh8,
                                            const float* __restrict__ a_src_n,
                                            const float* __restrict__ a_dst_n,
                                            const int* __restrict__ offs,
                                            const int* __restrict__ deg_arr,
                                            const int* __restrict__ src_list,
                                            const float* __restrict__ gat_bias,
                                            __half* __restrict__ x2h,
                                            float* __restrict__ den_inv) {
  __shared__ __align__(16) float s_al[CHUNK * 4];
  __shared__ int s_src[CHUNK];
  __shared__ __half s_tr[256];
  int n = blockIdx.x, lane = threadIdx.x;
  int off = offs[n], dg = deg_arr[n], cnt = dg + 1;
  float4 ad = *(const float4*)&a_dst_n[n * 4];
  int h = lane & 3;
  unsigned loff = 4u * (unsigned)lane;   // 32-bit gather offsets (saddr form)
  float acc0 = 0.f, acc1 = 0.f, acc2 = 0.f, acc3 = 0.f;

  if (cnt <= 64) {
    float e0 = 0.f, e1 = 0.f, e2 = 0.f, e3 = 0.f;
    if (lane < cnt) {
      int src = (lane < dg) ? src_list[off + lane] : n;
      float4 as = *(const float4*)&a_src_n[src * 4];
      e0 = __expf(lrelu(as.x + ad.x));
      e1 = __expf(lrelu(as.y + ad.y));
      e2 = __expf(lrelu(as.z + ad.z));
      e3 = __expf(lrelu(as.w + ad.w));
      s_src[lane] = src;
    }
    float s0 = e0, s1 = e1, s2 = e2, s3 = e3;
#pragma unroll
    for (int o = 32; o >= 1; o >>= 1) {
      s0 += __shfl_xor(s0, o, 64);
      s1 += __shfl_xor(s1, o, 64);
      s2 += __shfl_xor(s2, o, 64);
      s3 += __shfl_xor(s3, o, 64);
    }
    float i0 = 1.f / (s0 + 1e-16f), i1 = 1.f / (s1 + 1e-16f);
    float i2 = 1.f / (s2 + 1e-16f), i3 = 1.f / (s3 + 1e-16f);
    if (lane == 0) *(float4*)&den_inv[n * 4] = make_float4(i0, i1, i2, i3);
    if (lane < cnt) {
      s_al[lane * 4 + 0] = e0 * i0;
      s_al[lane * 4 + 1] = e1 * i1;
      s_al[lane * 4 + 2] = e2 * i2;
      s_al[lane * 4 + 3] = e3 * i3;
    }
    __syncthreads();
    int j = 0;
    for (; j + 8 <= cnt; j += 8) {
      unsigned oA = ((unsigned)s_src[j + 0] << 8) + loff;
      unsigned oB = ((unsigned)s_src[j + 1] << 8) + loff;
      unsigned oC = ((unsigned)s_src[j + 2] << 8) + loff;
      unsigned oD = ((unsigned)s_src[j + 3] << 8) + loff;
      unsigned oE = ((unsigned)s_src[j + 4] << 8) + loff;
      unsigned oF = ((unsigned)s_src[j + 5] << 8) + loff;
      unsigned oG = ((unsigned)s_src[j + 6] << 8) + loff;
      unsigned oH = ((unsigned)s_src[j + 7] << 8) + loff;
      unsigned rA = *(const unsigned*)&xh8[oA];
      unsigned rB = *(const unsigned*)&xh8[oB];
      unsigned rC = *(const unsigned*)&xh8[oC];
      unsigned rD = *(const unsigned*)&xh8[oD];
      unsigned rE = *(const unsigned*)&xh8[oE];
      unsigned rF = *(const unsigned*)&xh8[oF];
      unsigned rG = *(const unsigned*)&xh8[oG];
      unsigned rH = *(const unsigned*)&xh8[oH];
      float aA = s_al[(j + 0) * 4 + h], aB = s_al[(j + 1) * 4 + h];
      float aC = s_al[(j + 2) * 4 + h], aD = s_al[(j + 3) * 4 + h];
      float aE = s_al[(j + 4) * 4 + h], aF = s_al[(j + 5) * 4 + h];
      float aG = s_al[(j + 6) * 4 + h], aH = s_al[(j + 7) * 4 + h];
      f32x2 p;
      p = __builtin_amdgcn_cvt_pk_f32_fp8((int)rA, 0); acc0 += aA * p[0]; acc1 += aA * p[1];
      p = __builtin_amdgcn_cvt_pk_f32_fp8((int)rA, 1); acc2 += aA * p[0]; acc3 += aA * p[1];
      p = __builtin_amdgcn_cvt_pk_f32_fp8((int)rB, 0); acc0 += aB * p[0]; acc1 += aB * p[1];
      p = __builtin_amdgcn_cvt_pk_f32_fp8((int)rB, 1); acc2 += aB * p[0]; acc3 += aB * p[1];
      p = __builtin_amdgcn_cvt_pk_f32_fp8((int)rC, 0); acc0 += aC * p[0]; acc1 += aC * p[1];
      p = __builtin_amdgcn_cvt_pk_f32_fp8((int)rC, 1); acc2 += aC * p[0]; acc3 += aC * p[1];
      p = __builtin_amdgcn_cvt_pk_f32_fp8((int)rD, 0); acc0 += aD * p[0]; acc1 += aD * p[1];
      p = __builtin_amdgcn_cvt_pk_f32_fp8((int)rD, 1); acc2 += aD * p[0]; acc3 += aD * p[1];
      p = __builtin_amdgcn_cvt_pk_f32_fp8((int)rE, 0); acc0 += aE * p[0]; acc1 += aE * p[1];
      p = __builtin_amdgcn_cvt_pk_f32_fp8((int)rE, 1); acc2 += aE * p[0]; acc3 += aE * p[1];
      p = __builtin_amdgcn_cvt_pk_f32_fp8((int)rF, 0); acc0 += aF * p[0]; acc1 += aF * p[1];
      p = __builtin_amdgcn_cvt_pk_f32_fp8((int)rF, 1); acc2 += aF * p[0]; acc3 += aF * p[1];
      p = __builtin_amdgcn_cvt_pk_f32_fp8((int)rG, 0); acc0 += aG * p[0]; acc1 += aG * p[1];
      p = __builtin_amdgcn_cvt_pk_f32_fp8((int)rG, 1); acc2 += aG * p[0]; acc3 += aG * p[1];
      p = __builtin_amdgcn_cvt_pk_f32_fp8((int)rH, 0); acc0 += aH * p[0]; acc1 += aH * p[1];
      p = __builtin_amdgcn_cvt_pk_f32_fp8((int)rH, 1); acc2 += aH * p[0]; acc3 += aH * p[1];
    }
    for (; j + 4 <= cnt; j += 4) {
      unsigned oA = ((unsigned)s_src[j] << 8) + loff;
      unsigned oB = ((unsigned)s_src[j + 1] << 8) + loff;
      unsigned oC = ((unsigned)s_src[j + 2] << 8) + loff;
      unsigned oD = ((unsigned)s_src[j + 3] << 8) + loff;
      unsigned rA = *(const unsigned*)&xh8[oA];
      unsigned rB = *(const unsigned*)&xh8[oB];
      unsigned rC = *(const unsigned*)&xh8[oC];
      unsigned rD = *(const unsigned*)&xh8[oD];
      float aA = s_al[j * 4 + h], aB = s_al[(j + 1) * 4 + h];
      float aC = s_al[(j + 2) * 4 + h], aD = s_al[(j + 3) * 4 + h];
      f32x2 p;
      p = __builtin_amdgcn_cvt_pk_f32_fp8((int)rA, 0); acc0 += aA * p[0]; acc1 += aA * p[1];
      p = __builtin_amdgcn_cvt_pk_f32_fp8((int)rA, 1); acc2 += aA * p[0]; acc3 += aA * p[1];
      p = __builtin_amdgcn_cvt_pk_f32_fp8((int)rB, 0); acc0 += aB * p[0]; acc1 += aB * p[1];
      p = __builtin_amdgcn_cvt_pk_f32_fp8((int)rB, 1); acc2 += aB * p[0]; acc3 += aB * p[1];
      p = __builtin_amdgcn_cvt_pk_f32_fp8((int)rC, 0); acc0 += aC * p[0]; acc1 += aC * p[1];
      p = __builtin_amdgcn_cvt_pk_f32_fp8((int)rC, 1); acc2 += aC * p[0]; acc3 += aC * p[1];
      p = __builtin_amdgcn_cvt_pk_f32_fp8((int)rD, 0); acc0 += aD * p[0]; acc1 += aD * p[1];
      p = __builtin_amdgcn_cvt_pk_f32_fp8((int)rD, 1); acc2 += aD * p[0]; acc3 += aD * p[1];
    }
    for (; j < cnt; j++) {
      unsigned oA = ((unsigned)s_src[j] << 8) + loff;
      unsigned rA = *(const unsigned*)&xh8[oA];
      float aA = s_al[j * 4 + h];
      f32x2 p;
      p = __builtin_amdgcn_cvt_pk_f32_fp8((int)rA, 0); acc0 += aA * p[0]; acc1 += aA * p[1];
      p = __builtin_amdgcn_cvt_pk_f32_fp8((int)rA, 1); acc2 += aA * p[0]; acc3 += aA * p[1];
    }
  } else {
    float s0 = 0.f, s1 = 0.f, s2 = 0.f, s3 = 0.f;
    for (int j = lane; j < cnt; j += 64) {
      int src = (j < dg) ? src_list[off + j] : n;
      float4 as = *(const float4*)&a_src_n[src * 4];
      s0 += __expf(lrelu(as.x + ad.x));
      s1 += __expf(lrelu(as.y + ad.y));
      s2 += __expf(lrelu(as.z + ad.z));
      s3 += __expf(lrelu(as.w + ad.w));
    }
#pragma unroll
    for (int o = 32; o >= 1; o >>= 1) {
      s0 += __shfl_xor(s0, o, 64);
      s1 += __shfl_xor(s1, o, 64);
      s2 += __shfl_xor(s2, o, 64);
      s3 += __shfl_xor(s3, o, 64);
    }
    float i0 = 1.f / (s0 + 1e-16f), i1 = 1.f / (s1 + 1e-16f);
    float i2 = 1.f / (s2 + 1e-16f), i3 = 1.f / (s3 + 1e-16f);
    if (lane == 0) *(float4*)&den_inv[n * 4] = make_float4(i0, i1, i2, i3);
    for (int cb = 0; cb < cnt; cb += CHUNK) {
      int clen = min(CHUNK, cnt - cb);
      for (int j = lane; j < clen; j += 64) {
        int jj = cb + j;
        int src = (jj < dg) ? src_list[off + jj] : n;
        float4 as = *(const float4*)&a_src_n[src * 4];
        s_src[j] = src;
        s_al[j * 4 + 0] = __expf(lrelu(as.x + ad.x)) * i0;
        s_al[j * 4 + 1] = __expf(lrelu(as.y + ad.y)) * i1;
        s_al[j * 4 + 2] = __expf(lrelu(as.z + ad.z)) * i2;
        s_al[j * 4 + 3] = __expf(lrelu(as.w + ad.w)) * i3;
      }
      __syncthreads();
      for (int j = 0; j < clen; j++) {
        unsigned oA = ((unsigned)s_src[j] << 8) + loff;
        unsigned rA = *(const unsigned*)&xh8[oA];
        float aA = s_al[j * 4 + h];
        f32x2 p;
        p = __builtin_amdgcn_cvt_pk_f32_fp8((int)rA, 0); acc0 += aA * p[0]; acc1 += aA * p[1];
        p = __builtin_amdgcn_cvt_pk_f32_fp8((int)rA, 1); acc2 += aA * p[0]; acc3 += aA * p[1];
      }
      __syncthreads();
    }
  }

  int cb0 = (lane & 3) * 64 + (lane >> 2);
  s_tr[cb0 +  0] = __float2half(acc0 + gat_bias[cb0 +  0]);
  s_tr[cb0 + 16] = __float2half(acc1 + gat_bias[cb0 + 16]);
  s_tr[cb0 + 32] = __float2half(acc2 + gat_bias[cb0 + 32]);
  s_tr[cb0 + 48] = __float2half(acc3 + gat_bias[cb0 + 48]);
  __syncthreads();
  uint2 u = *(const uint2*)&s_tr[4 * lane];
  *(uint2*)&x2h[(size_t)n * 256 + 4 * lane] = u;
}

// ---------------- K4: per-graph tail — 512 threads (2 waves/SIMD) ------------
// LDS-capped at 1 block/CU either way; 8 waves double latency hiding on
// every phase (the measured 50 us was 1-wave/SIMD exposure, not BW).
// Stats/pool use row-interleaved partials + LDS combine (fp32 order change
// only, ~1e-7 vs the fp8-dominated 0.0039 tolerance).
__global__ __launch_bounds__(512) void k_tail(const int* __restrict__ gcnt,
                                              const int* __restrict__ goff,
                                              const float* __restrict__ gn_w,
                                              const float* __restrict__ gn_b,
                                              const float* __restrict__ gn_ms,
                                              const __half* __restrict__ x2h,
                                              const _Float16* __restrict__ a1w,
                                              const float* __restrict__ att1_b,
                                              const float* __restrict__ att2_w,
                                              const float* __restrict__ att2_b,
                                              const float* __restrict__ fc1_w,
                                              const float* __restrict__ fc1_b,
                                              const float* __restrict__ out_w,
                                              const float* __restrict__ out_b,
                                              const int* __restrict__ ei,
                                              const float* __restrict__ a_src_n,
                                              const float* __restrict__ a_dst_n,
                                              const float* __restrict__ den_inv,
                                              float* __restrict__ alpha_out,
                                              float* __restrict__ outp) {
  __shared__ __align__(16) __half s_x[GLDS * SXP];   // ~147.8 KB, bank-padded
  __shared__ __align__(16) float s_sc[256];
  __shared__ __align__(16) float s_sh[256];
  __shared__ float s_gate[GMAX];
  __shared__ __align__(16) float pool_s[256];
  __shared__ float hred[128];
  __shared__ float red[8];
  __shared__ float s_pa[512];
  __shared__ float s_pb[512];
  int g = blockIdx.x, tid = threadIdx.x, lane = tid & 63, wid = tid >> 6;
  int cnt = gcnt[g], start = goff[g];
  int am = lane & 15, quad = lane >> 4;

  if (cnt <= GLDS) {
    // ---- pass 1a: coalesced stage HBM -> LDS (16 B/lane, 4-deep, 16 rows) ---
    {
      int cg = tid & 31, r16 = tid >> 5;   // 16 row groups x 32 channel groups
      const __half* p = x2h + (size_t)start * 256 + cg * 8;
      int i = r16;
      for (; i + 48 < cnt; i += 64) {
        uint4 v0 = *(const uint4*)&p[(size_t)(i +  0) * 256];
        uint4 v1 = *(const uint4*)&p[(size_t)(i + 16) * 256];
        uint4 v2 = *(const uint4*)&p[(size_t)(i + 32) * 256];
        uint4 v3 = *(const uint4*)&p[(size_t)(i + 48) * 256];
        *(uint4*)&s_x[(i +  0) * SXP + cg * 8] = v0;
        *(uint4*)&s_x[(i + 16) * SXP + cg * 8] = v1;
        *(uint4*)&s_x[(i + 32) * SXP + cg * 8] = v2;
        *(uint4*)&s_x[(i + 48) * SXP + cg * 8] = v3;
      }
      for (; i < cnt; i += 16) {
        uint4 v = *(const uint4*)&p[(size_t)i * 256];
        *(uint4*)&s_x[i * SXP + cg * 8] = v;
      }
    }
    __syncthreads();

    // ---- pass 1b: stats partials (channel, half) -> combine ----
    {
      int c = tid & 255, hf = tid >> 8;
      float S = 0.f, S2 = 0.f;
      int i = hf;
      for (; i + 6 < cnt; i += 8) {
        float v0 = __half2float(s_x[(i + 0) * SXP + c]);
        float v1 = __half2float(s_x[(i + 2) * SXP + c]);
        float v2 = __half2float(s_x[(i + 4) * SXP + c]);
        float v3 = __half2float(s_x[(i + 6) * SXP + c]);
        S  += (v0 + v1) + (v2 + v3);
        S2 += (v0 * v0 + v1 * v1) + (v2 * v2 + v3 * v3);
      }
      for (; i < cnt; i += 2) {
        float v = __half2float(s_x[i * SXP + c]);
        S += v; S2 += v * v;
      }
      s_pa[tid] = S;
      s_pb[tid] = S2;
    }
    __syncthreads();
    if (tid < 256) {
      int c = tid;
      float S = s_pa[c] + s_pa[c + 256];
      float S2 = s_pb[c] + s_pb[c + 256];
      float fc = fmaxf((float)cnt, 1.f);
      float mean = S / fc;
      float mm = mean * gn_ms[c];
      float var = fmaxf(S2 / fc - 2.f * mm * mean + mm * mm, 0.f);
      float sc = gn_w[c] / sqrtf(var + GEPS);
      s_sc[c] = sc;
      s_sh[c] = gn_b[c] - sc * mm;
    }
    __syncthreads();

    // ---- gate MLP from LDS: 8 waves x 16 nodes via MFMA ----
    float b1 = att1_b[am], w2 = att2_w[am], b2 = att2_b[0];
    const _Float16* bp = a1w + am * 256 + quad * 8;
    for (int i0 = wid * 16; i0 < cnt; i0 += 128) {
      int li = i0 + am;
      if (li > cnt - 1) li = cnt - 1;
      const __half* xp = &s_x[li * SXP + quad * 8];
      f32x4 ga = (f32x4){0.f, 0.f, 0.f, 0.f};
#pragma unroll
      for (int kb = 0; kb < 8; kb++) {
        f16x8 xv = *(const f16x8*)(xp + kb * 32);
        int cb = quad * 8 + kb * 32;
        float4 sc0 = *(const float4*)&s_sc[cb];
        float4 sc1 = *(const float4*)&s_sc[cb + 4];
        float4 sh0 = *(const float4*)&s_sh[cb];
        float4 sh1 = *(const float4*)&s_sh[cb + 4];
        f16x8 a;
        a[0] = (_Float16)fmaxf(sc0.x * (float)xv[0] + sh0.x, 0.f);
        a[1] = (_Float16)fmaxf(sc0.y * (float)xv[1] + sh0.y, 0.f);
        a[2] = (_Float16)fmaxf(sc0.z * (float)xv[2] + sh0.z, 0.f);
        a[3] = (_Float16)fmaxf(sc0.w * (float)xv[3] + sh0.w, 0.f);
        a[4] = (_Float16)fmaxf(sc1.x * (float)xv[4] + sh1.x, 0.f);
        a[5] = (_Float16)fmaxf(sc1.y * (float)xv[5] + sh1.y, 0.f);
        a[6] = (_Float16)fmaxf(sc1.z * (float)xv[6] + sh1.z, 0.f);
        a[7] = (_Float16)fmaxf(sc1.w * (float)xv[7] + sh1.w, 0.f);
        f16x8 b = *(const f16x8*)(bp + kb * 32);
        ga = __builtin_amdgcn_mfma_f32_16x16x32_f16(a, b, ga, 0, 0, 0);
      }
#pragma unroll
      for (int r = 0; r < 4; r++) {
        float t = w2 * fmaxf(ga[r] + b1, 0.f);
#pragma unroll
        for (int o = 1; o < 16; o <<= 1) t += __shfl_xor(t, o, 64);
        if (am == 0) {
          int li2 = i0 + quad * 4 + r;
          if (li2 < cnt) s_gate[li2] = __expf(1.f / (1.f + __expf(-(t + b2))));
        }
      }
    }
    __syncthreads();

    // ---- gate softmax denominator (512-thread reduce) ----
    float ls = 0.f;
    for (int i = tid; i < cnt; i += 512) ls += s_gate[i];
#pragma unroll
    for (int o = 32; o >= 1; o >>= 1) ls += __shfl_xor(ls, o, 64);
    if (lane == 0) red[wid] = ls;
    __syncthreads();
    float rden = 1.f / (((red[0] + red[1]) + (red[2] + red[3])) +
                        ((red[4] + red[5]) + (red[6] + red[7])) + 1e-16f);

    // ---- weighted pool partials (channel, half) -> combine ----
    {
      int c = tid & 255, hf = tid >> 8;
      float a0 = 0.f, a1_ = 0.f, a2 = 0.f, a3 = 0.f;
      int i = hf;
      for (; i + 6 < cnt; i += 8) {
        float v0 = __half2float(s_x[(i + 0) * SXP + c]);
        float v1 = __half2float(s_x[(i + 2) * SXP + c]);
        float v2 = __half2float(s_x[(i + 4) * SXP + c]);
        float v3 = __half2float(s_x[(i + 6) * SXP + c]);
        float sc = s_sc[c], sh = s_sh[c];
        a0 += s_gate[i + 0] * fmaxf(sc * v0 + sh, 0.f);
        a1_ += s_gate[i + 2] * fmaxf(sc * v1 + sh, 0.f);
        a2 += s_gate[i + 4] * fmaxf(sc * v2 + sh, 0.f);
        a3 += s_gate[i + 6] * fmaxf(sc * v3 + sh, 0.f);
      }
      for (; i < cnt; i += 2)
        a0 += s_gate[i] * fmaxf(s_sc[c] * __half2float(s_x[i * SXP + c]) + s_sh[c], 0.f);
      s_pa[tid] = (a0 + a1_) + (a2 + a3);
    }
    __syncthreads();
    if (tid < 256) pool_s[tid] = (s_pa[tid] + s_pa[tid + 256]) * rden;
  } else {
    // ---- fallback: 512-safe global 3-pass path (cnt > GLDS, ~never) ----
    if (tid < 256) {
      int c = tid;
      const __half* p = x2h + (size_t)start * 256 + c;
      float S = 0.f, S2 = 0.f;
      for (int i = 0; i < cnt; i++) { float v = __half2float(p[(size_t)i * 256]); S += v; S2 += v * v; }
      float fc = fmaxf((float)cnt, 1.f);
      float mean = S / fc;
      float mm = mean * gn_ms[c];
      float var = fmaxf(S2 / fc - 2.f * mm * mean + mm * mm, 0.f);
      float sc = gn_w[c] / sqrtf(var + GEPS);
      s_sc[c] = sc;
      s_sh[c] = gn_b[c] - sc * mm;
    }
    __syncthreads();

    float b1 = att1_b[am], w2 = att2_w[am], b2 = att2_b[0];
    const _Float16* bp = a1w + am * 256 + quad * 8;
    for (int i0 = wid * 16; i0 < cnt; i0 += 128) {
      int node = start + i0 + am;
      if (node > NN - 1) node = NN - 1;
      const __half* xp = x2h + (size_t)node * 256 + quad * 8;
      f32x4 ga = (f32x4){0.f, 0.f, 0.f, 0.f};
#pragma unroll
      for (int kb = 0; kb < 8; kb++) {
        f16x8 xv = *(const f16x8*)(xp + kb * 32);
        int cb = quad * 8 + kb * 32;
        float4 sc0 = *(const float4*)&s_sc[cb];
        float4 sc1 = *(const float4*)&s_sc[cb + 4];
        float4 sh0 = *(const float4*)&s_sh[cb];
        float4 sh1 = *(const float4*)&s_sh[cb + 4];
        f16x8 a;
        a[0] = (_Float16)fmaxf(sc0.x * (float)xv[0] + sh0.x, 0.f);
        a[1] = (_Float16)fmaxf(sc0.y * (float)xv[1] + sh0.y, 0.f);
        a[2] = (_Float16)fmaxf(sc0.z * (float)xv[2] + sh0.z, 0.f);
        a[3] = (_Float16)fmaxf(sc0.w * (float)xv[3] + sh0.w, 0.f);
        a[4] = (_Float16)fmaxf(sc1.x * (float)xv[4] + sh1.x, 0.f);
        a[5] = (_Float16)fmaxf(sc1.y * (float)xv[5] + sh1.y, 0.f);
        a[6] = (_Float16)fmaxf(sc1.z * (float)xv[6] + sh1.z, 0.f);
        a[7] = (_Float16)fmaxf(sc1.w * (float)xv[7] + sh1.w, 0.f);
        f16x8 b = *(const f16x8*)(bp + kb * 32);
        ga = __builtin_amdgcn_mfma_f32_16x16x32_f16(a, b, ga, 0, 0, 0);
      }
#pragma unroll
      for (int r = 0; r < 4; r++) {
        float t = w2 * fmaxf(ga[r] + b1, 0.f);
#pragma unroll
        for (int o = 1; o < 16; o <<= 1) t += __shfl_xor(t, o, 64);
        if (am == 0) {
          int li = i0 + quad * 4 + r;
          if (li < cnt && li < GMAX)
            s_gate[li] = __expf(1.f / (1.f + __expf(-(t + b2))));
        }
      }
    }
    __syncthreads();

    float ls = 0.f;
    for (int i = tid; i < cnt; i += 512) ls += (i < GMAX) ? s_gate[i] : 0.f;
#pragma unroll
    for (int o = 32; o >= 1; o >>= 1) ls += __shfl_xor(ls, o, 64);
    if (lane == 0) red[wid] = ls;
    __syncthreads();
    float rden = 1.f / (((red[0] + red[1]) + (red[2] + red[3])) +
                        ((red[4] + red[5]) + (red[6] + red[7])) + 1e-16f);

    if (tid < 256) {
      int c = tid;
      float sc = s_sc[c], sh = s_sh[c];
      const __half* p = x2h + (size_t)start * 256 + c;
      float a0 = 0.f;
      for (int i = 0; i < cnt; i++) {
        float w = (i < GMAX) ? s_gate[i] : 0.f;
        a0 += w * fmaxf(sc * __half2float(p[(size_t)i * 256]) + sh, 0.f);
      }
      pool_s[c] = a0 * rden;
    }
  }
  __syncthreads();

  // ---- fc1 + out head (8 waves x 16 rows) ----
  float4 psv = *(const float4*)&pool_s[4 * lane];
  for (int j0 = 0; j0 < 16; j0++) {
    int j = wid * 16 + j0;
    float4 w = *(const float4*)&fc1_w[j * 256 + 4 * lane];
    float d = w.x * psv.x + w.y * psv.y + w.z * psv.z + w.w * psv.w;
#pragma unroll
    for (int o = 32; o >= 1; o >>= 1) d += __shfl_xor(d, o, 64);
    if (lane == 0) hred[j] = fmaxf(d + fc1_b[j], 0.f) * out_w[j];
  }
  __syncthreads();
  if (tid < 128) {
    float v = hred[tid];
#pragma unroll
    for (int o = 32; o >= 1; o >>= 1) v += __shfl_xor(v, o, 64);
    if (lane == 0) red[wid] = v;
  }
  __syncthreads();
  if (tid == 0) outp[g] = 1.f / (1.f + __expf(-(red[0] + red[1] + out_b[0])));

  // ---- alpha edge slab: 512 threads, 4 edges in flight per thread -----------
  {
    int base = g * EPT;
    int end = min(base + EPT, NE + NN);
    int idx = base + tid;
    for (; idx + 1536 < end; idx += 2048) {
      int i0 = idx, i1 = idx + 512, i2 = idx + 1024, i3 = idx + 1536;
      int s0, d0, s1, d1, s2, d2, s3, d3;
      if (i0 < NE) { s0 = ei[i0]; d0 = ei[NE + i0]; } else { s0 = i0 - NE; d0 = s0; }
      if (i1 < NE) { s1 = ei[i1]; d1 = ei[NE + i1]; } else { s1 = i1 - NE; d1 = s1; }
      if (i2 < NE) { s2 = ei[i2]; d2 = ei[NE + i2]; } else { s2 = i2 - NE; d2 = s2; }
      if (i3 < NE) { s3 = ei[i3]; d3 = ei[NE + i3]; } else { s3 = i3 - NE; d3 = s3; }
      float4 as0 = *(const float4*)&a_src_n[s0 * 4];
      float4 ad0 = *(const float4*)&a_dst_n[d0 * 4];
      float4 iv0 = *(const float4*)&den_inv[d0 * 4];
      float4 as1 = *(const float4*)&a_src_n[s1 * 4];
      float4 ad1 = *(const float4*)&a_dst_n[d1 * 4];
      float4 iv1 = *(const float4*)&den_inv[d1 * 4];
      float4 as2 = *(const float4*)&a_src_n[s2 * 4];
      float4 ad2 = *(const float4*)&a_dst_n[d2 * 4];
      float4 iv2 = *(const float4*)&den_inv[d2 * 4];
      float4 as3 = *(const float4*)&a_src_n[s3 * 4];
      float4 ad3 = *(const float4*)&a_dst_n[d3 * 4];
      float4 iv3 = *(const float4*)&den_inv[d3 * 4];
      float4 a;
      a.x = __expf(lrelu(as0.x + ad0.x)) * iv0.x;
      a.y = __expf(lrelu(as0.y + ad0.y)) * iv0.y;
      a.z = __expf(lrelu(as0.z + ad0.z)) * iv0.z;
      a.w = __expf(lrelu(as0.w + ad0.w)) * iv0.w;
      *(float4*)&alpha_out[(size_t)i0 * 4] = a;
      a.x = __expf(lrelu(as1.x + ad1.x)) * iv1.x;
      a.y = __expf(lrelu(as1.y + ad1.y)) * iv1.y;
      a.z = __expf(lrelu(as1.z + ad1.z)) * iv1.z;
      a.w = __expf(lrelu(as1.w + ad1.w)) * iv1.w;
      *(float4*)&alpha_out[(size_t)i1 * 4] = a;
      a.x = __expf(lrelu(as2.x + ad2.x)) * iv2.x;
      a.y = __expf(lrelu(as2.y + ad2.y)) * iv2.y;
      a.z = __expf(lrelu(as2.z + ad2.z)) * iv2.z;
      a.w = __expf(lrelu(as2.w + ad2.w)) * iv2.w;
      *(float4*)&alpha_out[(size_t)i2 * 4] = a;
      a.x = __expf(lrelu(as3.x + ad3.x)) * iv3.x;
      a.y = __expf(lrelu(as3.y + ad3.y)) * iv3.y;
      a.z = __expf(lrelu(as3.z + ad3.z)) * iv3.z;
      a.w = __expf(lrelu(as3.w + ad3.w)) * iv3.w;
      *(float4*)&alpha_out[(size_t)i3 * 4] = a;
    }
    for (; idx < end; idx += 512) {
      int s, d;
      if (idx < NE) { s = ei[idx]; d = ei[NE + idx]; }
      else          { s = idx - NE; d = s; }
      float4 as = *(const float4*)&a_src_n[s * 4];
      float4 ad = *(const float4*)&a_dst_n[d * 4];
      float4 iv = *(const float4*)&den_inv[d * 4];
      float4 a;
      a.x = __expf(lrelu(as.x + ad.x)) * iv.x;
      a.y = __expf(lrelu(as.y + ad.y)) * iv.y;
      a.z = __expf(lrelu(as.z + ad.z)) * iv.z;
      a.w = __expf(lrelu(as.w + ad.w)) * iv.w;
      *(float4*)&alpha_out[(size_t)idx * 4] = a;
    }
  }
}

// -----------------------------------------------------------------------------
extern "C" void kernel_launch(void* const* d_in, const int* in_sizes, int n_in,
                              void* d_out, int out_size, void* d_ws, size_t ws_size,
                              hipStream_t stream) {
  const float* x        = (const float*)d_in[0];
  const int*   ei       = (const int*)d_in[1];
  const int*   batch    = (const int*)d_in[2];
  const float* lin_w    = (const float*)d_in[3];
  const float* att_src  = (const float*)d_in[4];
  const float* att_dst  = (const float*)d_in[5];
  const float* gat_bias = (const float*)d_in[6];
  const float* gn_w     = (const float*)d_in[7];
  const float* gn_b     = (const float*)d_in[8];
  const float* gn_ms    = (const float*)d_in[9];
  const float* fc1_w    = (const float*)d_in[10];
  const float* fc1_b    = (const float*)d_in[11];
  const float* out_w    = (const float*)d_in[12];
  const float* out_b    = (const float*)d_in[13];
  const float* att1_w   = (const float*)d_in[14];
  const float* att1_b   = (const float*)d_in[15];
  const float* att2_w   = (const float*)d_in[16];
  const float* att2_b   = (const float*)d_in[17];

  float* outp  = (float*)d_out;       // [256]
  float* alpha = outp + NG;           // [(E+N)*4]

  char* wsb = (char*)d_ws;
  size_t o = 0;
  auto A = [&](size_t bytes) -> char* {
    char* p = wsb + o;
    o += (bytes + 255) & ~(size_t)255;
    return p;
  };
  unsigned char* xh8 = (unsigned char*)A((size_t)NN * 256);
  __half*   x2h      = (__half*)A((size_t)NN * 256 * 2);
  _Float16* wh       = (_Float16*)A((size_t)256 * 64 * 2);
  _Float16* a1w      = (_Float16*)A((size_t)16 * 256 * 2);
  _Float16* watt     = (_Float16*)A((size_t)16 * 64 * 2);
  float* a_src_n  = (float*)A((size_t)NN * 4 * 4);
  float* a_dst_n  = (float*)A((size_t)NN * 4 * 4);
  float* den_inv  = (float*)A((size_t)NN * 4 * 4);
  int*   deg      = (int*)A((size_t)NN * 4);
  int*   gcnt     = (int*)A((size_t)NG * 4);
  int*   offs     = (int*)A((size_t)NN * 4);
  int*   goff     = (int*)A((size_t)NG * 4);
  int*   src_list = (int*)A((size_t)NE * 4);
  int2*  ebuf     = (int2*)A((size_t)NB * CAP * 8);
  int*   bucket_cnt  = (int*)A((size_t)NB * 4);

  k_misc<<<22, 256, 0, stream>>>(lin_w, wh, att1_w, a1w, att_src, att_dst, watt,
                                 batch, goff, gcnt, bucket_cnt);
  k_linbin<<<NLINB + NAB, 256, 0, stream>>>(x, wh, watt, xh8, a_src_n, a_dst_n,
                                            ei, bucket_cnt, ebuf);
  k_binB<<<NB, 256, 0, stream>>>(ebuf, bucket_cnt, deg, offs, src_list);
  k_gat<<<NN, 64, 0, stream>>>(xh8, a_src_n, a_dst_n, offs, deg, src_list,
                               gat_bias, x2h, den_inv);
  k_tail<<<NG, 512, 0, stream>>>(gcnt, goff, gn_w, gn_b, gn_ms, x2h,
                                 a1w, att1_b, att2_w, att2_b, fc1_w, fc1_b,
                                 out_w, out_b, ei, a_src_n, a_dst_n, den_inv,
                                 alpha, outp);
}